// Round 3
// baseline (2360.473 us; speedup 1.0000x reference)
//
#include <hip/hip_runtime.h>

typedef unsigned short u16;
typedef unsigned int u32;
typedef __bf16 bf16x8 __attribute__((ext_vector_type(8)));
typedef float f32x4 __attribute__((ext_vector_type(4)));

#define NN 50000
#define EE 600000
#define GG 256
#define LL 5

__device__ __forceinline__ float b2f(u16 u) {
  unsigned int v = ((unsigned int)u) << 16;
  return __builtin_bit_cast(float, v);
}
__device__ __forceinline__ u16 f2b(float f) {
  unsigned int u = __builtin_bit_cast(unsigned int, f);
  u += 0x7FFFu + ((u >> 16) & 1u);
  return (u16)(u >> 16);
}

// ---------- dtype detect: flag=1 means floating inputs are fp32 ----------
__global__ void k_detect(const u32* __restrict__ w, int* __restrict__ flag) {
  __shared__ int sh[256];
  u32 v = w[threadIdx.x];
  u32 lo = v & 0xFFFFu;
  u32 e = (lo >> 7) & 0xFFu;  // bf16 exponent field of the low half
  sh[threadIdx.x] = (e >= 0x60u && e <= 0x7Fu) ? 1 : 0;
  __syncthreads();
  for (int s = 128; s > 0; s >>= 1) {
    if (threadIdx.x < (unsigned)s) sh[threadIdx.x] += sh[threadIdx.x + s];
    __syncthreads();
  }
  if (threadIdx.x == 0) flag[0] = (sh[0] < 128) ? 1 : 0;
}

__global__ void k_cvt(const void* __restrict__ src, u16* __restrict__ dst, int n,
                      const int* __restrict__ flag) {
  int i = blockIdx.x * 256 + threadIdx.x;
  if (i >= n) return;
  if (flag[0]) dst[i] = f2b(((const float*)src)[i]);
  else dst[i] = ((const u16*)src)[i];
}

// ---------------- CSR build ----------------
__global__ void k_deg(const int* __restrict__ ei, int* __restrict__ deg) {
  int e = blockIdx.x * 256 + threadIdx.x;
  if (e < EE) atomicAdd(&deg[ei[EE + e]], 1);
}

__global__ void k_scan(const int* __restrict__ deg, int* __restrict__ rowp,
                       int* __restrict__ cursor, int n) {
  __shared__ int sh[1024];
  __shared__ int carry;
  if (threadIdx.x == 0) carry = 0;
  __syncthreads();
  for (int base = 0; base < n; base += 1024) {
    int i = base + (int)threadIdx.x;
    int v = (i < n) ? deg[i] : 0;
    sh[threadIdx.x] = v;
    __syncthreads();
    for (int s = 1; s < 1024; s <<= 1) {
      int t = (threadIdx.x >= (unsigned)s) ? sh[threadIdx.x - s] : 0;
      __syncthreads();
      sh[threadIdx.x] += t;
      __syncthreads();
    }
    if (i < n) {
      int rp = carry + sh[threadIdx.x] - v;
      rowp[i] = rp;
      cursor[i] = rp;
    }
    __syncthreads();
    if (threadIdx.x == 1023) carry += sh[1023];
    __syncthreads();
  }
  if (threadIdx.x == 0) rowp[n] = carry;
}

__global__ void k_fill(const int* __restrict__ ei, int* __restrict__ cursor,
                       int* __restrict__ eid) {
  int e = blockIdx.x * 256 + threadIdx.x;
  if (e < EE) {
    int d = ei[EE + e];
    int pos = atomicAdd(&cursor[d], 1);
    eid[pos] = e;
  }
}

// ---------------- atom embed (+ fused pool accumulation of h0) ----------------
__global__ void k_atom(const int* __restrict__ x, const u16* __restrict__ aemb,
                       u16* __restrict__ h, const int* __restrict__ batch,
                       float* __restrict__ rep) {
  int idx = blockIdx.x * 256 + threadIdx.x;
  if (idx >= NN * 128) return;
  int n = idx >> 7, f = idx & 127;
  float acc = 0.f;
#pragma unroll
  for (int j = 0; j < 9; ++j) {
    int xv = x[n * 9 + j];
    acc += b2f(aemb[(j * 128 + xv) * 128 + f]);
  }
  h[idx] = f2b(acc);
  atomicAdd(&rep[batch[n] * 128 + f], acc);
}

__global__ void k_cnt(const int* __restrict__ batch, int* __restrict__ cnt) {
  int n = blockIdx.x * 256 + threadIdx.x;
  if (n < NN) atomicAdd(&cnt[batch[n]], 1);
}

// ------- pull aggregation; emits A = (1+eps)*h + sum relu(h[src]+e) in bf16 -------
__global__ void k_pull(const u16* __restrict__ h, const int* __restrict__ ei,
                       const int* __restrict__ eattr, const int* __restrict__ rowp,
                       const int* __restrict__ eid, const u16* __restrict__ bond,
                       const u16* __restrict__ epsv, int layer,
                       u16* __restrict__ amat) {
  int node = blockIdx.x * 2 + (threadIdx.x >> 7);
  int f = threadIdx.x & 127;
  if (node >= NN) return;
  int p0 = rowp[node], p1 = rowp[node + 1];
  float acc = 0.f;
  for (int p = p0; p < p1; ++p) {
    int e = eid[p];
    int s = ei[e];
    int a0 = eattr[e * 3], a1 = eattr[e * 3 + 1], a2 = eattr[e * 3 + 2];
    float emb = b2f(bond[a0 * 128 + f]) + b2f(bond[(128 + a1) * 128 + f]) +
                b2f(bond[(256 + a2) * 128 + f]);
    float m = b2f(h[s * 128 + f]) + emb;
    acc += fmaxf(m, 0.f);
  }
  float epsf = 1.0f + b2f(epsv[layer]);
  float own = b2f(h[node * 128 + f]);
  amat[node * 128 + f] = f2b(epsf * own + acc);
}

// ---------------- GEMM1: z0 = amat @ W1 + b1  (bf16 out) ----------------
__global__ __launch_bounds__(256, 2)
void k_gemm1(const u16* __restrict__ amat, const u16* __restrict__ W1,
             const u16* __restrict__ b1, u16* __restrict__ z0) {
  __shared__ u16 As[128 * 72];
  __shared__ u16 Bs[128 * 72];
  const int tid = threadIdx.x;
  const int r0 = blockIdx.x * 128;
  const int nc = blockIdx.y * 128;
  const int w = tid >> 6, lane = tid & 63, l15 = lane & 15, q = lane >> 4;
  const int wr = (w & 1) * 64, wc = (w >> 1) * 64;
  f32x4 acc[4][4];
#pragma unroll
  for (int i = 0; i < 4; ++i)
#pragma unroll
    for (int j = 0; j < 4; ++j) acc[i][j] = {0.f, 0.f, 0.f, 0.f};

  for (int ks = 0; ks < 2; ++ks) {
    const int k0 = ks * 64;
    for (int idx = tid; idx < 2048; idx += 256) {
      const int r = idx >> 4, c4 = (idx & 15) << 2;
      const int gr = r0 + r;
      ushort4 ov;
      if (gr < NN) {
        ov = *(const ushort4*)(amat + gr * 128 + k0 + c4);
      } else {
        ov.x = ov.y = ov.z = ov.w = 0;
      }
      *(ushort4*)(As + r * 72 + c4) = ov;
    }
    for (int idx = tid; idx < 2048; idx += 256) {
      const int kk = idx >> 5, n4 = (idx & 31) << 2;
      const ushort4 wv = *(const ushort4*)(W1 + (k0 + kk) * 256 + nc + n4);
      Bs[(n4 + 0) * 72 + kk] = wv.x;
      Bs[(n4 + 1) * 72 + kk] = wv.y;
      Bs[(n4 + 2) * 72 + kk] = wv.z;
      Bs[(n4 + 3) * 72 + kk] = wv.w;
    }
    __syncthreads();
#pragma unroll
    for (int kk = 0; kk < 64; kk += 32) {
      const int kf = kk + q * 8;
      bf16x8 a[4], b[4];
#pragma unroll
      for (int i = 0; i < 4; ++i) a[i] = *(const bf16x8*)(As + (wr + i * 16 + l15) * 72 + kf);
#pragma unroll
      for (int j = 0; j < 4; ++j) b[j] = *(const bf16x8*)(Bs + (wc + j * 16 + l15) * 72 + kf);
#pragma unroll
      for (int i = 0; i < 4; ++i)
#pragma unroll
        for (int j = 0; j < 4; ++j)
          acc[i][j] = __builtin_amdgcn_mfma_f32_16x16x32_bf16(a[i], b[j], acc[i][j], 0, 0, 0);
    }
    __syncthreads();
  }
#pragma unroll
  for (int j = 0; j < 4; ++j) {
    const int c = wc + j * 16 + l15;
    const float bias = b2f(b1[nc + c]);
#pragma unroll
    for (int i = 0; i < 4; ++i) {
      const int gr = r0 + wr + i * 16 + q * 4;
#pragma unroll
      for (int rg = 0; rg < 4; ++rg) {
        if (gr + rg < NN) z0[(gr + rg) * 256 + nc + c] = f2b(acc[i][j][rg] + bias);
      }
    }
  }
}

// -------- column stats: sum / sumsq over rows of bf16 matrix [NN x C] --------
__global__ void k_colstats(const u16* __restrict__ Z, int C,
                           float* __restrict__ sum, float* __restrict__ sq) {
  const int nseg = 256 / C;
  const int rpt = 64 / nseg;
  const int c = threadIdx.x & (C - 1);
  const int rseg = threadIdx.x / C;
  int r0 = blockIdx.x * 64 + rseg * rpt;
  int r1 = r0 + rpt;
  if (r1 > NN) r1 = NN;
  float s = 0.f, q = 0.f;
  for (int r = r0; r < r1; ++r) {
    float v = b2f(Z[r * C + c]);
    s += v;
    q += v * v;
  }
  atomicAdd(&sum[c], s);
  atomicAdd(&sq[c], q);
}

__global__ void k_bnfin(const float* __restrict__ bnsum, const float* __restrict__ bnsq,
                        const u16* __restrict__ g, const u16* __restrict__ b,
                        float* __restrict__ mean, float* __restrict__ rsg,
                        float* __restrict__ bb) {
  int t = threadIdx.x;
  float m = bnsum[t] * (1.0f / NN);
  float var = bnsq[t] * (1.0f / NN) - m * m;
  float rs = rsqrtf(var + 1e-5f);
  mean[t] = m;
  rsg[t] = rs * b2f(g[t]);
  bb[t] = b2f(b[t]);
}

// ---------------- GEMM2: hpre = relu(BN1(z0)) @ W2 + b2 (bf16 out) ----------------
__global__ __launch_bounds__(256, 2)
void k_gemm2(const u16* __restrict__ z0, const float* __restrict__ mean1,
             const float* __restrict__ rsg1, const float* __restrict__ bb1,
             const u16* __restrict__ W2, const u16* __restrict__ b2,
             u16* __restrict__ hpre) {
  __shared__ u16 As[128 * 72];
  __shared__ u16 Bs[128 * 72];
  const int tid = threadIdx.x;
  const int r0 = blockIdx.x * 128;
  const int w = tid >> 6, lane = tid & 63, l15 = lane & 15, q = lane >> 4;
  const int wr = (w & 1) * 64, wc = (w >> 1) * 64;
  f32x4 acc[4][4];
#pragma unroll
  for (int i = 0; i < 4; ++i)
#pragma unroll
    for (int j = 0; j < 4; ++j) acc[i][j] = {0.f, 0.f, 0.f, 0.f};

  for (int ks = 0; ks < 4; ++ks) {
    const int k0 = ks * 64;
    for (int idx = tid; idx < 2048; idx += 256) {
      const int r = idx >> 4, c4 = (idx & 15) << 2;
      const int gr = r0 + r;
      const int k = k0 + c4;
      ushort4 ov;
      if (gr < NN) {
        const ushort4 zv = *(const ushort4*)(z0 + gr * 256 + k);
        const float4 mv = *(const float4*)(mean1 + k);
        const float4 rv = *(const float4*)(rsg1 + k);
        const float4 bv = *(const float4*)(bb1 + k);
        ov.x = f2b(fmaxf((b2f(zv.x) - mv.x) * rv.x + bv.x, 0.f));
        ov.y = f2b(fmaxf((b2f(zv.y) - mv.y) * rv.y + bv.y, 0.f));
        ov.z = f2b(fmaxf((b2f(zv.z) - mv.z) * rv.z + bv.z, 0.f));
        ov.w = f2b(fmaxf((b2f(zv.w) - mv.w) * rv.w + bv.w, 0.f));
      } else {
        ov.x = ov.y = ov.z = ov.w = 0;
      }
      *(ushort4*)(As + r * 72 + c4) = ov;
    }
    for (int idx = tid; idx < 2048; idx += 256) {
      const int kk = idx >> 5, n4 = (idx & 31) << 2;
      const ushort4 wv = *(const ushort4*)(W2 + (k0 + kk) * 128 + n4);
      Bs[(n4 + 0) * 72 + kk] = wv.x;
      Bs[(n4 + 1) * 72 + kk] = wv.y;
      Bs[(n4 + 2) * 72 + kk] = wv.z;
      Bs[(n4 + 3) * 72 + kk] = wv.w;
    }
    __syncthreads();
#pragma unroll
    for (int kk = 0; kk < 64; kk += 32) {
      const int kf = kk + q * 8;
      bf16x8 a[4], b[4];
#pragma unroll
      for (int i = 0; i < 4; ++i) a[i] = *(const bf16x8*)(As + (wr + i * 16 + l15) * 72 + kf);
#pragma unroll
      for (int j = 0; j < 4; ++j) b[j] = *(const bf16x8*)(Bs + (wc + j * 16 + l15) * 72 + kf);
#pragma unroll
      for (int i = 0; i < 4; ++i)
#pragma unroll
        for (int j = 0; j < 4; ++j)
          acc[i][j] = __builtin_amdgcn_mfma_f32_16x16x32_bf16(a[i], b[j], acc[i][j], 0, 0, 0);
    }
    __syncthreads();
  }
#pragma unroll
  for (int j = 0; j < 4; ++j) {
    const int c = wc + j * 16 + l15;
    const float bias = b2f(b2[c]);
#pragma unroll
    for (int i = 0; i < 4; ++i) {
      const int gr = r0 + wr + i * 16 + q * 4;
#pragma unroll
      for (int rg = 0; rg < 4; ++rg) {
        if (gr + rg < NN) hpre[(gr + rg) * 128 + c] = f2b(acc[i][j][rg] + bias);
      }
    }
  }
}

// ------- BN2 apply + relu + write h + fused pool accumulation -------
__global__ void k_bnapply(const u16* __restrict__ hpre, const float* __restrict__ mean2,
                          const float* __restrict__ rsg2, const float* __restrict__ bb2,
                          u16* __restrict__ h, const int* __restrict__ batch,
                          float* __restrict__ rep, int dorelu) {
  int idx = blockIdx.x * 256 + threadIdx.x;
  if (idx >= NN * 128) return;
  int f = idx & 127;
  float v = (b2f(hpre[idx]) - mean2[f]) * rsg2[f] + bb2[f];
  if (dorelu) v = fmaxf(v, 0.f);
  h[idx] = f2b(v);
  atomicAdd(&rep[batch[idx >> 7] * 128 + f], v);
}

__global__ void k_rep(float* __restrict__ rep, const int* __restrict__ cnt) {
  int idx = blockIdx.x * 256 + threadIdx.x;  // GG*128
  int g = idx >> 7;
  int c = cnt[g];
  rep[idx] = rep[idx] / (float)(c > 0 ? c : 1);
}

// ---------------- FC head ----------------
__global__ void k_fc1(const float* __restrict__ rep, const u16* __restrict__ W,
                      const u16* __restrict__ bias, float* __restrict__ out) {
  __shared__ float a[128];
  int g = blockIdx.x, t = threadIdx.x;
  if (t < 128) a[t] = rep[g * 128 + t];
  __syncthreads();
  float a0 = 0, a1 = 0, a2 = 0, a3 = 0;
  for (int k = 0; k < 128; ++k) {
    float r = a[k];
    const u16* w = W + k * 1024 + t;
    a0 += r * b2f(w[0]);
    a1 += r * b2f(w[256]);
    a2 += r * b2f(w[512]);
    a3 += r * b2f(w[768]);
  }
  out[g * 1024 + t]       = fmaxf(a0 + b2f(bias[t]), 0.f);
  out[g * 1024 + t + 256] = fmaxf(a1 + b2f(bias[t + 256]), 0.f);
  out[g * 1024 + t + 512] = fmaxf(a2 + b2f(bias[t + 512]), 0.f);
  out[g * 1024 + t + 768] = fmaxf(a3 + b2f(bias[t + 768]), 0.f);
}

__global__ void k_fc2(const float* __restrict__ z, const u16* __restrict__ W,
                      const u16* __restrict__ bias, float* __restrict__ out) {
  __shared__ float a[1024];
  int g = blockIdx.x, t = threadIdx.x;
  for (int i = t; i < 1024; i += 256) a[i] = z[g * 1024 + i];
  __syncthreads();
  float a0 = 0, a1 = 0, a2 = 0, a3 = 0;
  for (int k = 0; k < 1024; ++k) {
    float r = a[k];
    const u16* w = W + k * 1024 + t;
    a0 += r * b2f(w[0]);
    a1 += r * b2f(w[256]);
    a2 += r * b2f(w[512]);
    a3 += r * b2f(w[768]);
  }
  out[g * 1024 + t]       = fmaxf(a0 + b2f(bias[t]), 0.f);
  out[g * 1024 + t + 256] = fmaxf(a1 + b2f(bias[t + 256]), 0.f);
  out[g * 1024 + t + 512] = fmaxf(a2 + b2f(bias[t + 512]), 0.f);
  out[g * 1024 + t + 768] = fmaxf(a3 + b2f(bias[t + 768]), 0.f);
}

__global__ void k_fc3(const float* __restrict__ z, const u16* __restrict__ W,
                      const u16* __restrict__ bias, float* __restrict__ out) {
  __shared__ float a[1024];
  int g = blockIdx.x, t = threadIdx.x;
  for (int i = t; i < 1024; i += 256) a[i] = z[g * 1024 + i];
  __syncthreads();
  float a0 = 0, a1 = 0;
  for (int k = 0; k < 1024; ++k) {
    float r = a[k];
    const u16* w = W + k * 512 + t;
    a0 += r * b2f(w[0]);
    a1 += r * b2f(w[256]);
  }
  out[g * 512 + t]       = fmaxf(a0 + b2f(bias[t]), 0.f);
  out[g * 512 + t + 256] = fmaxf(a1 + b2f(bias[t + 256]), 0.f);
}

__global__ void k_fc4(const float* __restrict__ z, const u16* __restrict__ W,
                      const u16* __restrict__ bias, void* __restrict__ out,
                      const int* __restrict__ flag) {
  int g = blockIdx.x, lane = threadIdx.x;  // 64 threads
  float acc = 0.f;
  for (int k = lane; k < 512; k += 64) acc += z[g * 512 + k] * b2f(W[k]);
  for (int off = 32; off > 0; off >>= 1) acc += __shfl_down(acc, off);
  if (lane == 0) {
    float r = acc + b2f(bias[0]);
    if (flag[0]) ((float*)out)[g] = r;
    else ((u16*)out)[g] = f2b(r);
  }
}

extern "C" void kernel_launch(void* const* d_in, const int* in_sizes, int n_in,
                              void* d_out, int out_size, void* d_ws, size_t ws_size,
                              hipStream_t stream) {
  const int* x     = (const int*)d_in[0];
  const int* ei    = (const int*)d_in[1];
  const int* eattr = (const int*)d_in[2];
  const int* batch = (const int*)d_in[3];

  char* ws = (char*)d_ws;
  size_t off = 0;
  auto alloc = [&](size_t bytes) -> void* {
    void* p = ws + off;
    off += (bytes + 255) & ~(size_t)255;
    return p;
  };
  int* flag = (int*)alloc(256);
  // canonical bf16 copies of all floating inputs (indices 4..22)
  u16* cvt[23];
  for (int i = 4; i <= 22; ++i) cvt[i] = (u16*)alloc((size_t)in_sizes[i] * 2);

  u16*   h      = (u16*)  alloc((size_t)NN * 128 * 2);   // 12.8 MB
  u16*   amat   = (u16*)  alloc((size_t)NN * 128 * 2);   // 12.8 MB (aliases hpre)
  u16*   z0     = (u16*)  alloc((size_t)NN * 256 * 2);   // 25.6 MB
  int*   deg    = (int*)  alloc((size_t)NN * 4);
  int*   cursor = (int*)  alloc((size_t)NN * 4);
  int*   rowp   = (int*)  alloc((size_t)(NN + 1) * 4);
  int*   eid    = (int*)  alloc((size_t)EE * 4);         // 2.4 MB
  float* bnbuf  = (float*)alloc(768 * 4);
  float* bnstat = (float*)alloc(1152 * 4);
  float* rep    = (float*)alloc((size_t)GG * 128 * 4);
  int*   cnt    = (int*)  alloc((size_t)GG * 4);
  float* fz1    = (float*)alloc((size_t)GG * 1024 * 4);
  float* fz2    = (float*)alloc((size_t)GG * 1024 * 4);
  float* fz3    = (float*)alloc((size_t)GG * 512 * 4);
  (void)ws_size; (void)n_in; (void)out_size;

  u16* hpre = amat;  // disjoint lifetimes

  float* bn1sum = bnbuf;
  float* bn1sq  = bnbuf + 256;
  float* bn2sum = bnbuf + 512;
  float* bn2sq  = bnbuf + 640;
  float* mean1  = bnstat;
  float* rsg1   = bnstat + 256;
  float* bb1    = bnstat + 512;
  float* mean2  = bnstat + 768;
  float* rsg2   = bnstat + 896;
  float* bb2    = bnstat + 1024;

  // dtype detect + convert all floating inputs to canonical bf16
  k_detect<<<1, 256, 0, stream>>>((const u32*)d_in[4], flag);
  for (int i = 4; i <= 22; ++i) {
    int n = in_sizes[i];
    k_cvt<<<(n + 255) / 256, 256, 0, stream>>>(d_in[i], cvt[i], n, flag);
  }
  const u16 *aembc = cvt[4], *bembc = cvt[5], *epsc = cvt[6], *w1c = cvt[7],
            *b1c = cvt[8], *g1c = cvt[9], *be1c = cvt[10], *w2c = cvt[11],
            *b2c = cvt[12], *bngc = cvt[13], *bnbc = cvt[14], *fw1 = cvt[15],
            *fb1 = cvt[16], *fw2 = cvt[17], *fb2 = cvt[18], *fw3 = cvt[19],
            *fb3 = cvt[20], *fw4 = cvt[21], *fb4 = cvt[22];

  hipMemsetAsync(deg, 0, (size_t)NN * 4, stream);
  hipMemsetAsync(rep, 0, (size_t)GG * 128 * 4, stream);
  hipMemsetAsync(cnt, 0, (size_t)GG * 4, stream);
  k_deg<<<(EE + 255) / 256, 256, 0, stream>>>(ei, deg);
  k_scan<<<1, 1024, 0, stream>>>(deg, rowp, cursor, NN);
  k_fill<<<(EE + 255) / 256, 256, 0, stream>>>(ei, cursor, eid);
  k_atom<<<(NN * 128) / 256, 256, 0, stream>>>(x, aembc, h, batch, rep);
  k_cnt<<<(NN + 255) / 256, 256, 0, stream>>>(batch, cnt);

  const int gx = (NN + 127) / 128;       // 391
  const int gs = (NN + 63) / 64;         // 782
  for (int l = 0; l < LL; ++l) {
    hipMemsetAsync(bnbuf, 0, 768 * 4, stream);
    k_pull<<<(NN + 1) / 2, 256, 0, stream>>>(h, ei, eattr, rowp, eid,
                                             bembc + (size_t)l * 3 * 128 * 128, epsc, l, amat);
    dim3 grid1(gx, 2);
    k_gemm1<<<grid1, 256, 0, stream>>>(amat, w1c, b1c, z0);
    k_colstats<<<gs, 256, 0, stream>>>(z0, 256, bn1sum, bn1sq);
    k_bnfin<<<1, 256, 0, stream>>>(bn1sum, bn1sq, g1c, be1c, mean1, rsg1, bb1);
    k_gemm2<<<gx, 256, 0, stream>>>(z0, mean1, rsg1, bb1, w2c, b2c, hpre);
    k_colstats<<<gs, 256, 0, stream>>>(hpre, 128, bn2sum, bn2sq);
    k_bnfin<<<1, 128, 0, stream>>>(bn2sum, bn2sq, bngc + l * 128, bnbc + l * 128,
                                   mean2, rsg2, bb2);
    k_bnapply<<<(NN * 128) / 256, 256, 0, stream>>>(hpre, mean2, rsg2, bb2, h, batch, rep,
                                                    (l < LL - 1) ? 1 : 0);
  }

  k_rep<<<(GG * 128) / 256, 256, 0, stream>>>(rep, cnt);
  k_fc1<<<GG, 256, 0, stream>>>(rep, fw1, fb1, fz1);
  k_fc2<<<GG, 256, 0, stream>>>(fz1, fw2, fb2, fz2);
  k_fc3<<<GG, 256, 0, stream>>>(fz2, fw3, fb3, fz3);
  k_fc4<<<GG, 64, 0, stream>>>(fz3, fw4, fb4, d_out, flag);
}

// Round 4
// 1955.878 us; speedup vs baseline: 1.2069x; 1.2069x over previous
//
#include <hip/hip_runtime.h>

typedef unsigned short u16;
typedef unsigned int u32;
typedef __bf16 bf16x8 __attribute__((ext_vector_type(8)));
typedef float f32x4 __attribute__((ext_vector_type(4)));

#define NN 50000
#define EE 600000
#define GG 256
#define LL 5

__device__ __forceinline__ float b2f(u16 u) {
  unsigned int v = ((unsigned int)u) << 16;
  return __builtin_bit_cast(float, v);
}
__device__ __forceinline__ u16 f2b(float f) {
  unsigned int u = __builtin_bit_cast(unsigned int, f);
  u += 0x7FFFu + ((u >> 16) & 1u);
  return (u16)(u >> 16);
}

// ---------- dtype detect: flag=1 means floating inputs are fp32 ----------
__global__ void k_detect(const u32* __restrict__ w, int* __restrict__ flag) {
  __shared__ int sh[256];
  u32 v = w[threadIdx.x];
  u32 lo = v & 0xFFFFu;
  u32 e = (lo >> 7) & 0xFFu;
  sh[threadIdx.x] = (e >= 0x60u && e <= 0x7Fu) ? 1 : 0;
  __syncthreads();
  for (int s = 128; s > 0; s >>= 1) {
    if (threadIdx.x < (unsigned)s) sh[threadIdx.x] += sh[threadIdx.x + s];
    __syncthreads();
  }
  if (threadIdx.x == 0) flag[0] = (sh[0] < 128) ? 1 : 0;
}

struct CvtArgs {
  const void* src[19];
  u16* dst[19];
  int cum[20];
};

__global__ void k_cvt_all(CvtArgs a, const int* __restrict__ flag) {
  int t = blockIdx.x * 256 + threadIdx.x;
  if (t >= a.cum[19]) return;
  int i = 0;
  while (t >= a.cum[i + 1]) ++i;
  int j = t - a.cum[i];
  if (flag[0]) a.dst[i][j] = f2b(((const float*)a.src[i])[j]);
  else a.dst[i][j] = ((const u16*)a.src[i])[j];
}

// ---------------- CSR build ----------------
__global__ void k_deg(const int* __restrict__ ei, int* __restrict__ deg) {
  int e = blockIdx.x * 256 + threadIdx.x;
  if (e < EE) atomicAdd(&deg[ei[EE + e]], 1);
}

__global__ void k_scan(const int* __restrict__ deg, int* __restrict__ rowp,
                       int* __restrict__ cursor, int n) {
  __shared__ int sh[1024];
  __shared__ int carry;
  if (threadIdx.x == 0) carry = 0;
  __syncthreads();
  for (int base = 0; base < n; base += 1024) {
    int i = base + (int)threadIdx.x;
    int v = (i < n) ? deg[i] : 0;
    sh[threadIdx.x] = v;
    __syncthreads();
    for (int s = 1; s < 1024; s <<= 1) {
      int t = (threadIdx.x >= (unsigned)s) ? sh[threadIdx.x - s] : 0;
      __syncthreads();
      sh[threadIdx.x] += t;
      __syncthreads();
    }
    if (i < n) {
      int rp = carry + sh[threadIdx.x] - v;
      rowp[i] = rp;
      cursor[i] = rp;
    }
    __syncthreads();
    if (threadIdx.x == 1023) carry += sh[1023];
    __syncthreads();
  }
  if (threadIdx.x == 0) rowp[n] = carry;
}

// fill CSR and pack per-position edge data: (src, a0, a1, a2)
__global__ void k_fill(const int* __restrict__ ei, const int* __restrict__ eattr,
                       int* __restrict__ cursor, int4* __restrict__ epack) {
  int e = blockIdx.x * 256 + threadIdx.x;
  if (e < EE) {
    int d = ei[EE + e];
    int pos = atomicAdd(&cursor[d], 1);
    epack[pos] = make_int4(ei[e], eattr[e * 3], eattr[e * 3 + 1], eattr[e * 3 + 2]);
  }
}

// ---------------- graph segment bounds (batch is sorted) ----------------
__global__ void k_gb(const int* __restrict__ batch, int* __restrict__ gstart,
                     int* __restrict__ gend) {
  int n = blockIdx.x * 256 + threadIdx.x;
  if (n < NN) {
    int b = batch[n];
    atomicMin(&gstart[b], n);
    atomicMax(&gend[b], n);
  }
}

// ---------------- atom embed ----------------
__global__ void k_atom(const int* __restrict__ x, const u16* __restrict__ aemb,
                       u16* __restrict__ h) {
  int idx = blockIdx.x * 256 + threadIdx.x;
  if (idx >= NN * 128) return;
  int n = idx >> 7, f = idx & 127;
  float acc = 0.f;
#pragma unroll
  for (int j = 0; j < 9; ++j) {
    int xv = x[n * 9 + j];
    acc += b2f(aemb[(j * 128 + xv) * 128 + f]);
  }
  h[idx] = f2b(acc);
}

// ------- pull: wave per node, 2 feats/lane, prefetched packed indices -------
__global__ __launch_bounds__(256)
void k_pull(const u16* __restrict__ h, const int* __restrict__ rowp,
            const int4* __restrict__ epack, const u16* __restrict__ bond,
            const u16* __restrict__ epsv, int layer, u16* __restrict__ amat) {
  const int lane = threadIdx.x & 63;
  const int node = blockIdx.x * 4 + (threadIdx.x >> 6);
  const int p0 = rowp[node], p1 = rowp[node + 1];
  const u16* bondB = bond + 16384;
  const u16* bondC = bond + 32768;
  float acc0 = 0.f, acc1 = 0.f;
  int4 cur = (p0 < p1) ? epack[p0] : make_int4(0, 0, 0, 0);
  for (int p = p0; p < p1; ++p) {
    int4 nxt = (p + 1 < p1) ? epack[p + 1] : cur;
    u32 hv  = *(const u32*)(h + cur.x * 128 + lane * 2);
    u32 e0v = *(const u32*)(bond + cur.y * 128 + lane * 2);
    u32 e1v = *(const u32*)(bondB + cur.z * 128 + lane * 2);
    u32 e2v = *(const u32*)(bondC + cur.w * 128 + lane * 2);
    float el = b2f((u16)e0v) + b2f((u16)e1v) + b2f((u16)e2v);
    float eh = b2f((u16)(e0v >> 16)) + b2f((u16)(e1v >> 16)) + b2f((u16)(e2v >> 16));
    acc0 += fmaxf(b2f((u16)hv) + el, 0.f);
    acc1 += fmaxf(b2f((u16)(hv >> 16)) + eh, 0.f);
    cur = nxt;
  }
  float epsf = 1.0f + b2f(epsv[layer]);
  u32 own = *(const u32*)(h + node * 128 + lane * 2);
  u32 o = (u32)f2b(epsf * b2f((u16)own) + acc0) |
          ((u32)f2b(epsf * b2f((u16)(own >> 16)) + acc1) << 16);
  *(u32*)(amat + node * 128 + lane * 2) = o;
}

// ---------------- GEMM1: z0 = amat @ W1 + b1 (bf16 out) + BN1 stats ----------------
__global__ __launch_bounds__(256, 2)
void k_gemm1(const u16* __restrict__ amat, const u16* __restrict__ W1,
             const u16* __restrict__ b1, u16* __restrict__ z0,
             float* __restrict__ bnsum, float* __restrict__ bnsq) {
  __shared__ u16 As[128 * 72];
  __shared__ u16 Bs[128 * 72];
  const int tid = threadIdx.x;
  const int r0 = blockIdx.x * 128;
  const int nc = blockIdx.y * 128;
  const int w = tid >> 6, lane = tid & 63, l15 = lane & 15, q = lane >> 4;
  const int wr = (w & 1) * 64, wc = (w >> 1) * 64;
  f32x4 acc[4][4];
#pragma unroll
  for (int i = 0; i < 4; ++i)
#pragma unroll
    for (int j = 0; j < 4; ++j) acc[i][j] = {0.f, 0.f, 0.f, 0.f};

  for (int ks = 0; ks < 2; ++ks) {
    const int k0 = ks * 64;
    for (int idx = tid; idx < 2048; idx += 256) {
      const int r = idx >> 4, c4 = (idx & 15) << 2;
      const int gr = r0 + r;
      ushort4 ov;
      if (gr < NN) {
        ov = *(const ushort4*)(amat + gr * 128 + k0 + c4);
      } else {
        ov.x = ov.y = ov.z = ov.w = 0;
      }
      *(ushort4*)(As + r * 72 + c4) = ov;
    }
    for (int idx = tid; idx < 2048; idx += 256) {
      const int kk = idx >> 5, n4 = (idx & 31) << 2;
      const ushort4 wv = *(const ushort4*)(W1 + (k0 + kk) * 256 + nc + n4);
      Bs[(n4 + 0) * 72 + kk] = wv.x;
      Bs[(n4 + 1) * 72 + kk] = wv.y;
      Bs[(n4 + 2) * 72 + kk] = wv.z;
      Bs[(n4 + 3) * 72 + kk] = wv.w;
    }
    __syncthreads();
#pragma unroll
    for (int kk = 0; kk < 64; kk += 32) {
      const int kf = kk + q * 8;
      bf16x8 a[4], b[4];
#pragma unroll
      for (int i = 0; i < 4; ++i) a[i] = *(const bf16x8*)(As + (wr + i * 16 + l15) * 72 + kf);
#pragma unroll
      for (int j = 0; j < 4; ++j) b[j] = *(const bf16x8*)(Bs + (wc + j * 16 + l15) * 72 + kf);
#pragma unroll
      for (int i = 0; i < 4; ++i)
#pragma unroll
        for (int j = 0; j < 4; ++j)
          acc[i][j] = __builtin_amdgcn_mfma_f32_16x16x32_bf16(a[i], b[j], acc[i][j], 0, 0, 0);
    }
    __syncthreads();
  }
  float* colAcc = (float*)As;  // 256 floats: sum[0..127], sumsq[128..255]
  colAcc[tid] = 0.f;
  __syncthreads();
#pragma unroll
  for (int j = 0; j < 4; ++j) {
    const int c = wc + j * 16 + l15;
    const float bias = b2f(b1[nc + c]);
    float ls = 0.f, lsq = 0.f;
#pragma unroll
    for (int i = 0; i < 4; ++i) {
      const int gr = r0 + wr + i * 16 + q * 4;
#pragma unroll
      for (int rg = 0; rg < 4; ++rg) {
        if (gr + rg < NN) {
          const float v = acc[i][j][rg] + bias;
          z0[(gr + rg) * 256 + nc + c] = f2b(v);
          ls += v;
          lsq += v * v;
        }
      }
    }
    atomicAdd(&colAcc[c], ls);
    atomicAdd(&colAcc[128 + c], lsq);
  }
  __syncthreads();
  if (tid < 128) {
    atomicAdd(&bnsum[nc + tid], colAcc[tid]);
    atomicAdd(&bnsq[nc + tid], colAcc[128 + tid]);
  }
}

// bnfin: reads stats, zeroes them for next layer, emits mean / rsqrt*g / beta
__global__ void k_bnfin(float* __restrict__ bnsum, float* __restrict__ bnsq,
                        const u16* __restrict__ g, const u16* __restrict__ b,
                        float* __restrict__ mean, float* __restrict__ rsg,
                        float* __restrict__ bb) {
  int t = threadIdx.x;
  float s = bnsum[t], q = bnsq[t];
  bnsum[t] = 0.f;
  bnsq[t] = 0.f;
  float m = s * (1.0f / NN);
  float var = q * (1.0f / NN) - m * m;
  float rs = rsqrtf(var + 1e-5f);
  mean[t] = m;
  rsg[t] = rs * b2f(g[t]);
  bb[t] = b2f(b[t]);
}

// ---------------- GEMM2: hpre = relu(BN1(z0)) @ W2 + b2 (bf16 out) + BN2 stats ----------------
__global__ __launch_bounds__(256, 2)
void k_gemm2(const u16* __restrict__ z0, const float* __restrict__ mean1,
             const float* __restrict__ rsg1, const float* __restrict__ bb1,
             const u16* __restrict__ W2, const u16* __restrict__ b2,
             u16* __restrict__ hpre, float* __restrict__ bnsum, float* __restrict__ bnsq) {
  __shared__ u16 As[128 * 72];
  __shared__ u16 Bs[128 * 72];
  const int tid = threadIdx.x;
  const int r0 = blockIdx.x * 128;
  const int w = tid >> 6, lane = tid & 63, l15 = lane & 15, q = lane >> 4;
  const int wr = (w & 1) * 64, wc = (w >> 1) * 64;
  f32x4 acc[4][4];
#pragma unroll
  for (int i = 0; i < 4; ++i)
#pragma unroll
    for (int j = 0; j < 4; ++j) acc[i][j] = {0.f, 0.f, 0.f, 0.f};

  for (int ks = 0; ks < 4; ++ks) {
    const int k0 = ks * 64;
    for (int idx = tid; idx < 2048; idx += 256) {
      const int r = idx >> 4, c4 = (idx & 15) << 2;
      const int gr = r0 + r;
      const int k = k0 + c4;
      ushort4 ov;
      if (gr < NN) {
        const ushort4 zv = *(const ushort4*)(z0 + gr * 256 + k);
        const float4 mv = *(const float4*)(mean1 + k);
        const float4 rv = *(const float4*)(rsg1 + k);
        const float4 bv = *(const float4*)(bb1 + k);
        ov.x = f2b(fmaxf((b2f(zv.x) - mv.x) * rv.x + bv.x, 0.f));
        ov.y = f2b(fmaxf((b2f(zv.y) - mv.y) * rv.y + bv.y, 0.f));
        ov.z = f2b(fmaxf((b2f(zv.z) - mv.z) * rv.z + bv.z, 0.f));
        ov.w = f2b(fmaxf((b2f(zv.w) - mv.w) * rv.w + bv.w, 0.f));
      } else {
        ov.x = ov.y = ov.z = ov.w = 0;
      }
      *(ushort4*)(As + r * 72 + c4) = ov;
    }
    for (int idx = tid; idx < 2048; idx += 256) {
      const int kk = idx >> 5, n4 = (idx & 31) << 2;
      const ushort4 wv = *(const ushort4*)(W2 + (k0 + kk) * 128 + n4);
      Bs[(n4 + 0) * 72 + kk] = wv.x;
      Bs[(n4 + 1) * 72 + kk] = wv.y;
      Bs[(n4 + 2) * 72 + kk] = wv.z;
      Bs[(n4 + 3) * 72 + kk] = wv.w;
    }
    __syncthreads();
#pragma unroll
    for (int kk = 0; kk < 64; kk += 32) {
      const int kf = kk + q * 8;
      bf16x8 a[4], b[4];
#pragma unroll
      for (int i = 0; i < 4; ++i) a[i] = *(const bf16x8*)(As + (wr + i * 16 + l15) * 72 + kf);
#pragma unroll
      for (int j = 0; j < 4; ++j) b[j] = *(const bf16x8*)(Bs + (wc + j * 16 + l15) * 72 + kf);
#pragma unroll
      for (int i = 0; i < 4; ++i)
#pragma unroll
        for (int j = 0; j < 4; ++j)
          acc[i][j] = __builtin_amdgcn_mfma_f32_16x16x32_bf16(a[i], b[j], acc[i][j], 0, 0, 0);
    }
    __syncthreads();
  }
  float* colAcc = (float*)As;
  colAcc[tid] = 0.f;
  __syncthreads();
#pragma unroll
  for (int j = 0; j < 4; ++j) {
    const int c = wc + j * 16 + l15;
    const float bias = b2f(b2[c]);
    float ls = 0.f, lsq = 0.f;
#pragma unroll
    for (int i = 0; i < 4; ++i) {
      const int gr = r0 + wr + i * 16 + q * 4;
#pragma unroll
      for (int rg = 0; rg < 4; ++rg) {
        if (gr + rg < NN) {
          const float v = acc[i][j][rg] + bias;
          hpre[(gr + rg) * 128 + c] = f2b(v);
          ls += v;
          lsq += v * v;
        }
      }
    }
    atomicAdd(&colAcc[c], ls);
    atomicAdd(&colAcc[128 + c], lsq);
  }
  __syncthreads();
  if (tid < 128) {
    atomicAdd(&bnsum[tid], colAcc[tid]);
    atomicAdd(&bnsq[tid], colAcc[128 + tid]);
  }
}

// ------- BN2 apply + relu + write h (vectorized x4) -------
__global__ void k_bnapply(const u16* __restrict__ hpre, const float* __restrict__ mean2,
                          const float* __restrict__ rsg2, const float* __restrict__ bb2,
                          u16* __restrict__ h, int dorelu) {
  int idx4 = (blockIdx.x * 256 + threadIdx.x) * 4;
  if (idx4 >= NN * 128) return;
  int f = idx4 & 127;
  const ushort4 hv = *(const ushort4*)(hpre + idx4);
  const float4 mv = *(const float4*)(mean2 + f);
  const float4 rv = *(const float4*)(rsg2 + f);
  const float4 bv = *(const float4*)(bb2 + f);
  float v0 = (b2f(hv.x) - mv.x) * rv.x + bv.x;
  float v1 = (b2f(hv.y) - mv.y) * rv.y + bv.y;
  float v2 = (b2f(hv.z) - mv.z) * rv.z + bv.z;
  float v3 = (b2f(hv.w) - mv.w) * rv.w + bv.w;
  if (dorelu) {
    v0 = fmaxf(v0, 0.f); v1 = fmaxf(v1, 0.f);
    v2 = fmaxf(v2, 0.f); v3 = fmaxf(v3, 0.f);
  }
  ushort4 ov;
  ov.x = f2b(v0); ov.y = f2b(v1); ov.z = f2b(v2); ov.w = f2b(v3);
  *(ushort4*)(h + idx4) = ov;
}

// ------- segment pooling over sorted batch: rep[g] += sum rows of h -------
__global__ void k_poolseg(const u16* __restrict__ h, const int* __restrict__ gstart,
                          const int* __restrict__ gend, float* __restrict__ rep) {
  int g = blockIdx.x, f = threadIdx.x;  // 128 threads
  int r0 = gstart[g], r1 = gend[g];
  float acc = 0.f;
  for (int r = r0; r <= r1; ++r) acc += b2f(h[r * 128 + f]);
  rep[g * 128 + f] += acc;
}

__global__ void k_rep(float* __restrict__ rep, const int* __restrict__ gstart,
                      const int* __restrict__ gend) {
  int idx = blockIdx.x * 256 + threadIdx.x;  // GG*128
  int g = idx >> 7;
  int c = gend[g] - gstart[g] + 1;
  if (c < 1) c = 1;
  rep[idx] = rep[idx] / (float)c;
}

// ---------------- FC head ----------------
__global__ void k_fc1(const float* __restrict__ rep, const u16* __restrict__ W,
                      const u16* __restrict__ bias, float* __restrict__ out) {
  __shared__ float a[128];
  int g = blockIdx.x, t = threadIdx.x;
  if (t < 128) a[t] = rep[g * 128 + t];
  __syncthreads();
  float a0 = 0, a1 = 0, a2 = 0, a3 = 0;
  for (int k = 0; k < 128; ++k) {
    float r = a[k];
    const u16* w = W + k * 1024 + t;
    a0 += r * b2f(w[0]);
    a1 += r * b2f(w[256]);
    a2 += r * b2f(w[512]);
    a3 += r * b2f(w[768]);
  }
  out[g * 1024 + t]       = fmaxf(a0 + b2f(bias[t]), 0.f);
  out[g * 1024 + t + 256] = fmaxf(a1 + b2f(bias[t + 256]), 0.f);
  out[g * 1024 + t + 512] = fmaxf(a2 + b2f(bias[t + 512]), 0.f);
  out[g * 1024 + t + 768] = fmaxf(a3 + b2f(bias[t + 768]), 0.f);
}

__global__ void k_fc2(const float* __restrict__ z, const u16* __restrict__ W,
                      const u16* __restrict__ bias, float* __restrict__ out) {
  __shared__ float a[1024];
  int g = blockIdx.x, t = threadIdx.x;
  for (int i = t; i < 1024; i += 256) a[i] = z[g * 1024 + i];
  __syncthreads();
  float a0 = 0, a1 = 0, a2 = 0, a3 = 0;
  for (int k = 0; k < 1024; ++k) {
    float r = a[k];
    const u16* w = W + k * 1024 + t;
    a0 += r * b2f(w[0]);
    a1 += r * b2f(w[256]);
    a2 += r * b2f(w[512]);
    a3 += r * b2f(w[768]);
  }
  out[g * 1024 + t]       = fmaxf(a0 + b2f(bias[t]), 0.f);
  out[g * 1024 + t + 256] = fmaxf(a1 + b2f(bias[t + 256]), 0.f);
  out[g * 1024 + t + 512] = fmaxf(a2 + b2f(bias[t + 512]), 0.f);
  out[g * 1024 + t + 768] = fmaxf(a3 + b2f(bias[t + 768]), 0.f);
}

__global__ void k_fc3(const float* __restrict__ z, const u16* __restrict__ W,
                      const u16* __restrict__ bias, float* __restrict__ out) {
  __shared__ float a[1024];
  int g = blockIdx.x, t = threadIdx.x;
  for (int i = t; i < 1024; i += 256) a[i] = z[g * 1024 + i];
  __syncthreads();
  float a0 = 0, a1 = 0;
  for (int k = 0; k < 1024; ++k) {
    float r = a[k];
    const u16* w = W + k * 512 + t;
    a0 += r * b2f(w[0]);
    a1 += r * b2f(w[256]);
  }
  out[g * 512 + t]       = fmaxf(a0 + b2f(bias[t]), 0.f);
  out[g * 512 + t + 256] = fmaxf(a1 + b2f(bias[t + 256]), 0.f);
}

__global__ void k_fc4(const float* __restrict__ z, const u16* __restrict__ W,
                      const u16* __restrict__ bias, void* __restrict__ out,
                      const int* __restrict__ flag) {
  int g = blockIdx.x, lane = threadIdx.x;  // 64 threads
  float acc = 0.f;
  for (int k = lane; k < 512; k += 64) acc += z[g * 512 + k] * b2f(W[k]);
  for (int off = 32; off > 0; off >>= 1) acc += __shfl_down(acc, off);
  if (lane == 0) {
    float r = acc + b2f(bias[0]);
    if (flag[0]) ((float*)out)[g] = r;
    else ((u16*)out)[g] = f2b(r);
  }
}

extern "C" void kernel_launch(void* const* d_in, const int* in_sizes, int n_in,
                              void* d_out, int out_size, void* d_ws, size_t ws_size,
                              hipStream_t stream) {
  const int* x     = (const int*)d_in[0];
  const int* ei    = (const int*)d_in[1];
  const int* eattr = (const int*)d_in[2];
  const int* batch = (const int*)d_in[3];

  char* ws = (char*)d_ws;
  size_t off = 0;
  auto alloc = [&](size_t bytes) -> void* {
    void* p = ws + off;
    off += (bytes + 255) & ~(size_t)255;
    return p;
  };
  int* flag = (int*)alloc(256);
  u16* cvt[23];
  CvtArgs ca;
  ca.cum[0] = 0;
  for (int i = 4; i <= 22; ++i) {
    cvt[i] = (u16*)alloc((size_t)in_sizes[i] * 2);
    ca.src[i - 4] = d_in[i];
    ca.dst[i - 4] = cvt[i];
    ca.cum[i - 3] = ca.cum[i - 4] + in_sizes[i];
  }

  u16*   h      = (u16*)  alloc((size_t)NN * 128 * 2);   // 12.8 MB
  u16*   amat   = (u16*)  alloc((size_t)NN * 128 * 2);   // 12.8 MB (aliases hpre)
  u16*   z0     = (u16*)  alloc((size_t)NN * 256 * 2);   // 25.6 MB
  int*   deg    = (int*)  alloc((size_t)NN * 4);
  int*   cursor = (int*)  alloc((size_t)NN * 4);
  int*   rowp   = (int*)  alloc((size_t)(NN + 1) * 4);
  int4*  epack  = (int4*) alloc((size_t)EE * 16);        // 9.6 MB
  float* bnbuf  = (float*)alloc(768 * 4);
  float* bnstat = (float*)alloc(1152 * 4);
  float* rep    = (float*)alloc((size_t)GG * 128 * 4);
  int*   gstart = (int*)  alloc((size_t)GG * 4);
  int*   gend   = (int*)  alloc((size_t)GG * 4);
  float* fz1    = (float*)alloc((size_t)GG * 1024 * 4);
  float* fz2    = (float*)alloc((size_t)GG * 1024 * 4);
  float* fz3    = (float*)alloc((size_t)GG * 512 * 4);
  (void)ws_size; (void)n_in; (void)out_size;

  u16* hpre = amat;  // disjoint lifetimes

  float* bn1sum = bnbuf;
  float* bn1sq  = bnbuf + 256;
  float* bn2sum = bnbuf + 512;
  float* bn2sq  = bnbuf + 640;
  float* mean1  = bnstat;
  float* rsg1   = bnstat + 256;
  float* bb1    = bnstat + 512;
  float* mean2  = bnstat + 768;
  float* rsg2   = bnstat + 896;
  float* bb2    = bnstat + 1024;

  k_detect<<<1, 256, 0, stream>>>((const u32*)d_in[4], flag);
  {
    int total = ca.cum[19];
    k_cvt_all<<<(total + 255) / 256, 256, 0, stream>>>(ca, flag);
  }
  const u16 *aembc = cvt[4], *bembc = cvt[5], *epsc = cvt[6], *w1c = cvt[7],
            *b1c = cvt[8], *g1c = cvt[9], *be1c = cvt[10], *w2c = cvt[11],
            *b2c = cvt[12], *bngc = cvt[13], *bnbc = cvt[14], *fw1 = cvt[15],
            *fb1 = cvt[16], *fw2 = cvt[17], *fb2 = cvt[18], *fw3 = cvt[19],
            *fb3 = cvt[20], *fw4 = cvt[21], *fb4 = cvt[22];

  hipMemsetAsync(deg, 0, (size_t)NN * 4, stream);
  hipMemsetAsync(rep, 0, (size_t)GG * 128 * 4, stream);
  hipMemsetAsync(gstart, 0x7F, (size_t)GG * 4, stream);
  hipMemsetAsync(gend, 0xFF, (size_t)GG * 4, stream);
  hipMemsetAsync(bnbuf, 0, 768 * 4, stream);
  k_deg<<<(EE + 255) / 256, 256, 0, stream>>>(ei, deg);
  k_scan<<<1, 1024, 0, stream>>>(deg, rowp, cursor, NN);
  k_fill<<<(EE + 255) / 256, 256, 0, stream>>>(ei, eattr, cursor, epack);
  k_gb<<<(NN + 255) / 256, 256, 0, stream>>>(batch, gstart, gend);
  k_atom<<<(NN * 128) / 256, 256, 0, stream>>>(x, aembc, h);
  k_poolseg<<<GG, 128, 0, stream>>>(h, gstart, gend, rep);

  const int gx = (NN + 127) / 128;  // 391
  for (int l = 0; l < LL; ++l) {
    k_pull<<<(NN + 3) / 4, 256, 0, stream>>>(h, rowp, epack,
                                             bembc + (size_t)l * 3 * 128 * 128, epsc, l, amat);
    dim3 grid1(gx, 2);
    k_gemm1<<<grid1, 256, 0, stream>>>(amat, w1c, b1c, z0, bn1sum, bn1sq);
    k_bnfin<<<1, 256, 0, stream>>>(bn1sum, bn1sq, g1c, be1c, mean1, rsg1, bb1);
    k_gemm2<<<gx, 256, 0, stream>>>(z0, mean1, rsg1, bb1, w2c, b2c, hpre, bn2sum, bn2sq);
    k_bnfin<<<1, 128, 0, stream>>>(bn2sum, bn2sq, bngc + l * 128, bnbc + l * 128,
                                   mean2, rsg2, bb2);
    k_bnapply<<<(NN * 128) / 1024, 256, 0, stream>>>(hpre, mean2, rsg2, bb2, h,
                                                     (l < LL - 1) ? 1 : 0);
    k_poolseg<<<GG, 128, 0, stream>>>(h, gstart, gend, rep);
  }

  k_rep<<<(GG * 128) / 256, 256, 0, stream>>>(rep, gstart, gend);
  k_fc1<<<GG, 256, 0, stream>>>(rep, fw1, fb1, fz1);
  k_fc2<<<GG, 256, 0, stream>>>(fz1, fw2, fb2, fz2);
  k_fc3<<<GG, 256, 0, stream>>>(fz2, fw3, fb3, fz3);
  k_fc4<<<GG, 64, 0, stream>>>(fz3, fw4, fb4, d_out, flag);
}

// Round 5
// 1306.527 us; speedup vs baseline: 1.8067x; 1.4970x over previous
//
#include <hip/hip_runtime.h>

typedef unsigned short u16;
typedef unsigned int u32;
typedef __bf16 bf16x8 __attribute__((ext_vector_type(8)));
typedef float f32x4 __attribute__((ext_vector_type(4)));

#define NN 50000
#define EE 600000
#define GG 256
#define LL 5

__device__ __forceinline__ float b2f(u16 u) {
  unsigned int v = ((unsigned int)u) << 16;
  return __builtin_bit_cast(float, v);
}
__device__ __forceinline__ u16 f2b(float f) {
  unsigned int u = __builtin_bit_cast(unsigned int, f);
  u += 0x7FFFu + ((u >> 16) & 1u);
  return (u16)(u >> 16);
}

// ---------- dtype detect: flag=1 means floating inputs are fp32 ----------
__global__ void k_detect(const u32* __restrict__ w, int* __restrict__ flag) {
  __shared__ int sh[256];
  u32 v = w[threadIdx.x];
  u32 lo = v & 0xFFFFu;
  u32 e = (lo >> 7) & 0xFFu;
  sh[threadIdx.x] = (e >= 0x60u && e <= 0x7Fu) ? 1 : 0;
  __syncthreads();
  for (int s = 128; s > 0; s >>= 1) {
    if (threadIdx.x < (unsigned)s) sh[threadIdx.x] += sh[threadIdx.x + s];
    __syncthreads();
  }
  if (threadIdx.x == 0) flag[0] = (sh[0] < 128) ? 1 : 0;
}

struct CvtArgs {
  const void* src[19];
  u16* dst[19];
  int cum[20];
};

__global__ void k_cvt_all(CvtArgs a, const int* __restrict__ flag) {
  int t = blockIdx.x * 256 + threadIdx.x;
  if (t >= a.cum[19]) return;
  int i = 0;
  while (t >= a.cum[i + 1]) ++i;
  int j = t - a.cum[i];
  if (flag[0]) a.dst[i][j] = f2b(((const float*)a.src[i])[j]);
  else a.dst[i][j] = ((const u16*)a.src[i])[j];
}

// ---------------- CSR build ----------------
__global__ void k_deg(const int* __restrict__ ei, int* __restrict__ deg) {
  int e = blockIdx.x * 256 + threadIdx.x;
  if (e < EE) atomicAdd(&deg[ei[EE + e]], 1);
}

__global__ void k_scan(const int* __restrict__ deg, int* __restrict__ rowp,
                       int* __restrict__ cursor, int n) {
  __shared__ int sh[1024];
  __shared__ int carry;
  if (threadIdx.x == 0) carry = 0;
  __syncthreads();
  for (int base = 0; base < n; base += 1024) {
    int i = base + (int)threadIdx.x;
    int v = (i < n) ? deg[i] : 0;
    sh[threadIdx.x] = v;
    __syncthreads();
    for (int s = 1; s < 1024; s <<= 1) {
      int t = (threadIdx.x >= (unsigned)s) ? sh[threadIdx.x - s] : 0;
      __syncthreads();
      sh[threadIdx.x] += t;
      __syncthreads();
    }
    if (i < n) {
      int rp = carry + sh[threadIdx.x] - v;
      rowp[i] = rp;
      cursor[i] = rp;
    }
    __syncthreads();
    if (threadIdx.x == 1023) carry += sh[1023];
    __syncthreads();
  }
  if (threadIdx.x == 0) rowp[n] = carry;
}

// fill CSR; pack edge as (src:16 | a0:7<<16 | a1:7<<23, a2)
__global__ void k_fill(const int* __restrict__ ei, const int* __restrict__ eattr,
                       int* __restrict__ cursor, uint2* __restrict__ epack) {
  int e = blockIdx.x * 256 + threadIdx.x;
  if (e < EE) {
    int d = ei[EE + e];
    int pos = atomicAdd(&cursor[d], 1);
    u32 src = (u32)ei[e];
    u32 a0 = (u32)eattr[e * 3], a1 = (u32)eattr[e * 3 + 1], a2 = (u32)eattr[e * 3 + 2];
    epack[pos] = make_uint2(src | (a0 << 16) | (a1 << 23), a2);
  }
}

// ---------------- graph segment bounds (batch is sorted) ----------------
__global__ void k_gb(const int* __restrict__ batch, int* __restrict__ gstart,
                     int* __restrict__ gend) {
  int n = blockIdx.x * 256 + threadIdx.x;
  if (n < NN) {
    int b = batch[n];
    atomicMin(&gstart[b], n);
    atomicMax(&gend[b], n);
  }
}

// ---------------- atom embed (2 feats/thread) ----------------
__global__ void k_atom(const int* __restrict__ x, const u16* __restrict__ aemb,
                       u16* __restrict__ h) {
  int idx = blockIdx.x * 256 + threadIdx.x;  // over NN*64
  if (idx >= NN * 64) return;
  int n = idx >> 6, f2 = (idx & 63) << 1;
  float a0 = 0.f, a1 = 0.f;
#pragma unroll
  for (int j = 0; j < 9; ++j) {
    int xv = x[n * 9 + j];
    u32 v = *(const u32*)(aemb + (j * 128 + xv) * 128 + f2);
    a0 += b2f((u16)v);
    a1 += b2f((u16)(v >> 16));
  }
  u32 o = (u32)f2b(a0) | ((u32)f2b(a1) << 16);
  *(u32*)(h + n * 128 + f2) = o;
}

// ------- pull: wave per node, 2 feats/lane, 4-edge groups for MLP -------
__global__ __launch_bounds__(256)
void k_pull(const u16* __restrict__ h, const int* __restrict__ rowp,
            const uint2* __restrict__ epack, const u16* __restrict__ bond,
            const u16* __restrict__ epsv, int layer, u16* __restrict__ amat) {
  const int lane = threadIdx.x & 63;
  const int node = blockIdx.x * 4 + (threadIdx.x >> 6);
  const int p0 = rowp[node], p1 = rowp[node + 1];
  const int lo = lane << 1;
  const u16* bondB = bond + 16384;
  const u16* bondC = bond + 32768;
  float acc0 = 0.f, acc1 = 0.f;
  int p = p0;
  for (; p + 4 <= p1; p += 4) {
    uint2 e0 = epack[p], e1 = epack[p + 1], e2 = epack[p + 2], e3 = epack[p + 3];
    u32 h0 = *(const u32*)(h + (size_t)(e0.x & 0xFFFFu) * 128 + lo);
    u32 h1 = *(const u32*)(h + (size_t)(e1.x & 0xFFFFu) * 128 + lo);
    u32 h2 = *(const u32*)(h + (size_t)(e2.x & 0xFFFFu) * 128 + lo);
    u32 h3 = *(const u32*)(h + (size_t)(e3.x & 0xFFFFu) * 128 + lo);
    u32 a0 = *(const u32*)(bond + ((e0.x >> 16) & 0x7Fu) * 128 + lo);
    u32 a1 = *(const u32*)(bond + ((e1.x >> 16) & 0x7Fu) * 128 + lo);
    u32 a2 = *(const u32*)(bond + ((e2.x >> 16) & 0x7Fu) * 128 + lo);
    u32 a3 = *(const u32*)(bond + ((e3.x >> 16) & 0x7Fu) * 128 + lo);
    u32 b0 = *(const u32*)(bondB + ((e0.x >> 23) & 0x7Fu) * 128 + lo);
    u32 b1 = *(const u32*)(bondB + ((e1.x >> 23) & 0x7Fu) * 128 + lo);
    u32 b2 = *(const u32*)(bondB + ((e2.x >> 23) & 0x7Fu) * 128 + lo);
    u32 b3 = *(const u32*)(bondB + ((e3.x >> 23) & 0x7Fu) * 128 + lo);
    u32 c0 = *(const u32*)(bondC + e0.y * 128 + lo);
    u32 c1 = *(const u32*)(bondC + e1.y * 128 + lo);
    u32 c2 = *(const u32*)(bondC + e2.y * 128 + lo);
    u32 c3 = *(const u32*)(bondC + e3.y * 128 + lo);
    acc0 += fmaxf(b2f((u16)h0) + b2f((u16)a0) + b2f((u16)b0) + b2f((u16)c0), 0.f);
    acc1 += fmaxf(b2f((u16)(h0 >> 16)) + b2f((u16)(a0 >> 16)) + b2f((u16)(b0 >> 16)) + b2f((u16)(c0 >> 16)), 0.f);
    acc0 += fmaxf(b2f((u16)h1) + b2f((u16)a1) + b2f((u16)b1) + b2f((u16)c1), 0.f);
    acc1 += fmaxf(b2f((u16)(h1 >> 16)) + b2f((u16)(a1 >> 16)) + b2f((u16)(b1 >> 16)) + b2f((u16)(c1 >> 16)), 0.f);
    acc0 += fmaxf(b2f((u16)h2) + b2f((u16)a2) + b2f((u16)b2) + b2f((u16)c2), 0.f);
    acc1 += fmaxf(b2f((u16)(h2 >> 16)) + b2f((u16)(a2 >> 16)) + b2f((u16)(b2 >> 16)) + b2f((u16)(c2 >> 16)), 0.f);
    acc0 += fmaxf(b2f((u16)h3) + b2f((u16)a3) + b2f((u16)b3) + b2f((u16)c3), 0.f);
    acc1 += fmaxf(b2f((u16)(h3 >> 16)) + b2f((u16)(a3 >> 16)) + b2f((u16)(b3 >> 16)) + b2f((u16)(c3 >> 16)), 0.f);
  }
  for (; p < p1; ++p) {
    uint2 e0 = epack[p];
    u32 h0 = *(const u32*)(h + (size_t)(e0.x & 0xFFFFu) * 128 + lo);
    u32 a0 = *(const u32*)(bond + ((e0.x >> 16) & 0x7Fu) * 128 + lo);
    u32 b0 = *(const u32*)(bondB + ((e0.x >> 23) & 0x7Fu) * 128 + lo);
    u32 c0 = *(const u32*)(bondC + e0.y * 128 + lo);
    acc0 += fmaxf(b2f((u16)h0) + b2f((u16)a0) + b2f((u16)b0) + b2f((u16)c0), 0.f);
    acc1 += fmaxf(b2f((u16)(h0 >> 16)) + b2f((u16)(a0 >> 16)) + b2f((u16)(b0 >> 16)) + b2f((u16)(c0 >> 16)), 0.f);
  }
  float epsf = 1.0f + b2f(epsv[layer]);
  u32 own = *(const u32*)(h + (size_t)node * 128 + lo);
  u32 o = (u32)f2b(epsf * b2f((u16)own) + acc0) |
          ((u32)f2b(epsf * b2f((u16)(own >> 16)) + acc1) << 16);
  *(u32*)(amat + (size_t)node * 128 + lo) = o;
}

// ---------------- GEMM1: z0 = amat @ W1 + b1 (bf16 out) + BN1 stats ----------------
__global__ __launch_bounds__(256, 2)
void k_gemm1(const u16* __restrict__ amat, const u16* __restrict__ W1,
             const u16* __restrict__ b1, u16* __restrict__ z0,
             float* __restrict__ bnsum, float* __restrict__ bnsq) {
  __shared__ u16 As[128 * 72];
  __shared__ u16 Bs[128 * 72];
  const int tid = threadIdx.x;
  const int r0 = blockIdx.x * 128;
  const int nc = blockIdx.y * 128;
  const int w = tid >> 6, lane = tid & 63, l15 = lane & 15, q = lane >> 4;
  const int wr = (w & 1) * 64, wc = (w >> 1) * 64;
  f32x4 acc[4][4];
#pragma unroll
  for (int i = 0; i < 4; ++i)
#pragma unroll
    for (int j = 0; j < 4; ++j) acc[i][j] = {0.f, 0.f, 0.f, 0.f};

  for (int ks = 0; ks < 2; ++ks) {
    const int k0 = ks * 64;
    for (int idx = tid; idx < 2048; idx += 256) {
      const int r = idx >> 4, c4 = (idx & 15) << 2;
      const int gr = r0 + r;
      ushort4 ov;
      if (gr < NN) {
        ov = *(const ushort4*)(amat + gr * 128 + k0 + c4);
      } else {
        ov.x = ov.y = ov.z = ov.w = 0;
      }
      *(ushort4*)(As + r * 72 + c4) = ov;
    }
    for (int idx = tid; idx < 2048; idx += 256) {
      const int kk = idx >> 5, n4 = (idx & 31) << 2;
      const ushort4 wv = *(const ushort4*)(W1 + (k0 + kk) * 256 + nc + n4);
      Bs[(n4 + 0) * 72 + kk] = wv.x;
      Bs[(n4 + 1) * 72 + kk] = wv.y;
      Bs[(n4 + 2) * 72 + kk] = wv.z;
      Bs[(n4 + 3) * 72 + kk] = wv.w;
    }
    __syncthreads();
#pragma unroll
    for (int kk = 0; kk < 64; kk += 32) {
      const int kf = kk + q * 8;
      bf16x8 a[4], b[4];
#pragma unroll
      for (int i = 0; i < 4; ++i) a[i] = *(const bf16x8*)(As + (wr + i * 16 + l15) * 72 + kf);
#pragma unroll
      for (int j = 0; j < 4; ++j) b[j] = *(const bf16x8*)(Bs + (wc + j * 16 + l15) * 72 + kf);
#pragma unroll
      for (int i = 0; i < 4; ++i)
#pragma unroll
        for (int j = 0; j < 4; ++j)
          acc[i][j] = __builtin_amdgcn_mfma_f32_16x16x32_bf16(a[i], b[j], acc[i][j], 0, 0, 0);
    }
    __syncthreads();
  }
  float* colAcc = (float*)As;
  colAcc[tid] = 0.f;
  __syncthreads();
#pragma unroll
  for (int j = 0; j < 4; ++j) {
    const int c = wc + j * 16 + l15;
    const float bias = b2f(b1[nc + c]);
    float ls = 0.f, lsq = 0.f;
#pragma unroll
    for (int i = 0; i < 4; ++i) {
      const int gr = r0 + wr + i * 16 + q * 4;
#pragma unroll
      for (int rg = 0; rg < 4; ++rg) {
        if (gr + rg < NN) {
          const float v = acc[i][j][rg] + bias;
          z0[(gr + rg) * 256 + nc + c] = f2b(v);
          ls += v;
          lsq += v * v;
        }
      }
    }
    atomicAdd(&colAcc[c], ls);
    atomicAdd(&colAcc[128 + c], lsq);
  }
  __syncthreads();
  if (tid < 128) {
    atomicAdd(&bnsum[nc + tid], colAcc[tid]);
    atomicAdd(&bnsq[nc + tid], colAcc[128 + tid]);
  }
}

// bnfin: reads stats, zeroes them for next layer, emits mean / rsqrt*g / beta
__global__ void k_bnfin(float* __restrict__ bnsum, float* __restrict__ bnsq,
                        const u16* __restrict__ g, const u16* __restrict__ b,
                        float* __restrict__ mean, float* __restrict__ rsg,
                        float* __restrict__ bb) {
  int t = threadIdx.x;
  float s = bnsum[t], q = bnsq[t];
  bnsum[t] = 0.f;
  bnsq[t] = 0.f;
  float m = s * (1.0f / NN);
  float var = q * (1.0f / NN) - m * m;
  float rs = rsqrtf(var + 1e-5f);
  mean[t] = m;
  rsg[t] = rs * b2f(g[t]);
  bb[t] = b2f(b[t]);
}

// ---------------- GEMM2: hpre = relu(BN1(z0)) @ W2 + b2 (bf16 out) + BN2 stats ----------------
__global__ __launch_bounds__(256, 2)
void k_gemm2(const u16* __restrict__ z0, const float* __restrict__ mean1,
             const float* __restrict__ rsg1, const float* __restrict__ bb1,
             const u16* __restrict__ W2, const u16* __restrict__ b2,
             u16* __restrict__ hpre, float* __restrict__ bnsum, float* __restrict__ bnsq) {
  __shared__ u16 As[128 * 72];
  __shared__ u16 Bs[128 * 72];
  const int tid = threadIdx.x;
  const int r0 = blockIdx.x * 128;
  const int w = tid >> 6, lane = tid & 63, l15 = lane & 15, q = lane >> 4;
  const int wr = (w & 1) * 64, wc = (w >> 1) * 64;
  f32x4 acc[4][4];
#pragma unroll
  for (int i = 0; i < 4; ++i)
#pragma unroll
    for (int j = 0; j < 4; ++j) acc[i][j] = {0.f, 0.f, 0.f, 0.f};

  for (int ks = 0; ks < 4; ++ks) {
    const int k0 = ks * 64;
    for (int idx = tid; idx < 2048; idx += 256) {
      const int r = idx >> 4, c4 = (idx & 15) << 2;
      const int gr = r0 + r;
      const int k = k0 + c4;
      ushort4 ov;
      if (gr < NN) {
        const ushort4 zv = *(const ushort4*)(z0 + gr * 256 + k);
        const float4 mv = *(const float4*)(mean1 + k);
        const float4 rv = *(const float4*)(rsg1 + k);
        const float4 bv = *(const float4*)(bb1 + k);
        ov.x = f2b(fmaxf((b2f(zv.x) - mv.x) * rv.x + bv.x, 0.f));
        ov.y = f2b(fmaxf((b2f(zv.y) - mv.y) * rv.y + bv.y, 0.f));
        ov.z = f2b(fmaxf((b2f(zv.z) - mv.z) * rv.z + bv.z, 0.f));
        ov.w = f2b(fmaxf((b2f(zv.w) - mv.w) * rv.w + bv.w, 0.f));
      } else {
        ov.x = ov.y = ov.z = ov.w = 0;
      }
      *(ushort4*)(As + r * 72 + c4) = ov;
    }
    for (int idx = tid; idx < 2048; idx += 256) {
      const int kk = idx >> 5, n4 = (idx & 31) << 2;
      const ushort4 wv = *(const ushort4*)(W2 + (k0 + kk) * 128 + n4);
      Bs[(n4 + 0) * 72 + kk] = wv.x;
      Bs[(n4 + 1) * 72 + kk] = wv.y;
      Bs[(n4 + 2) * 72 + kk] = wv.z;
      Bs[(n4 + 3) * 72 + kk] = wv.w;
    }
    __syncthreads();
#pragma unroll
    for (int kk = 0; kk < 64; kk += 32) {
      const int kf = kk + q * 8;
      bf16x8 a[4], b[4];
#pragma unroll
      for (int i = 0; i < 4; ++i) a[i] = *(const bf16x8*)(As + (wr + i * 16 + l15) * 72 + kf);
#pragma unroll
      for (int j = 0; j < 4; ++j) b[j] = *(const bf16x8*)(Bs + (wc + j * 16 + l15) * 72 + kf);
#pragma unroll
      for (int i = 0; i < 4; ++i)
#pragma unroll
        for (int j = 0; j < 4; ++j)
          acc[i][j] = __builtin_amdgcn_mfma_f32_16x16x32_bf16(a[i], b[j], acc[i][j], 0, 0, 0);
    }
    __syncthreads();
  }
  float* colAcc = (float*)As;
  colAcc[tid] = 0.f;
  __syncthreads();
#pragma unroll
  for (int j = 0; j < 4; ++j) {
    const int c = wc + j * 16 + l15;
    const float bias = b2f(b2[c]);
    float ls = 0.f, lsq = 0.f;
#pragma unroll
    for (int i = 0; i < 4; ++i) {
      const int gr = r0 + wr + i * 16 + q * 4;
#pragma unroll
      for (int rg = 0; rg < 4; ++rg) {
        if (gr + rg < NN) {
          const float v = acc[i][j][rg] + bias;
          hpre[(gr + rg) * 128 + c] = f2b(v);
          ls += v;
          lsq += v * v;
        }
      }
    }
    atomicAdd(&colAcc[c], ls);
    atomicAdd(&colAcc[128 + c], lsq);
  }
  __syncthreads();
  if (tid < 128) {
    atomicAdd(&bnsum[tid], colAcc[tid]);
    atomicAdd(&bnsq[tid], colAcc[128 + tid]);
  }
}

// ------- BN2 apply + relu + write h (vectorized x4) -------
__global__ void k_bnapply(const u16* __restrict__ hpre, const float* __restrict__ mean2,
                          const float* __restrict__ rsg2, const float* __restrict__ bb2,
                          u16* __restrict__ h, int dorelu) {
  int idx4 = (blockIdx.x * 256 + threadIdx.x) * 4;
  if (idx4 >= NN * 128) return;
  int f = idx4 & 127;
  const ushort4 hv = *(const ushort4*)(hpre + idx4);
  const float4 mv = *(const float4*)(mean2 + f);
  const float4 rv = *(const float4*)(rsg2 + f);
  const float4 bv = *(const float4*)(bb2 + f);
  float v0 = (b2f(hv.x) - mv.x) * rv.x + bv.x;
  float v1 = (b2f(hv.y) - mv.y) * rv.y + bv.y;
  float v2 = (b2f(hv.z) - mv.z) * rv.z + bv.z;
  float v3 = (b2f(hv.w) - mv.w) * rv.w + bv.w;
  if (dorelu) {
    v0 = fmaxf(v0, 0.f); v1 = fmaxf(v1, 0.f);
    v2 = fmaxf(v2, 0.f); v3 = fmaxf(v3, 0.f);
  }
  ushort4 ov;
  ov.x = f2b(v0); ov.y = f2b(v1); ov.z = f2b(v2); ov.w = f2b(v3);
  *(ushort4*)(h + idx4) = ov;
}

// ------- segment pooling, 4 blocks per graph, atomic fp32 into rep -------
__global__ void k_poolseg(const u16* __restrict__ h, const int* __restrict__ gstart,
                          const int* __restrict__ gend, float* __restrict__ rep) {
  int g = blockIdx.x >> 2, part = blockIdx.x & 3, f = threadIdx.x;  // 128 threads
  int r0 = gstart[g], r1 = gend[g] + 1;
  int len = r1 - r0;
  if (len <= 0) return;
  int chunk = (len + 3) >> 2;
  int s = r0 + part * chunk;
  int e = s + chunk; if (e > r1) e = r1;
  float acc = 0.f;
  for (int r = s; r < e; ++r) acc += b2f(h[r * 128 + f]);
  if (s < e) atomicAdd(&rep[g * 128 + f], acc);
}

__global__ void k_rep(float* __restrict__ rep, const int* __restrict__ gstart,
                      const int* __restrict__ gend) {
  int idx = blockIdx.x * 256 + threadIdx.x;  // GG*128
  int g = idx >> 7;
  int c = gend[g] - gstart[g] + 1;
  if (c < 1) c = 1;
  rep[idx] = rep[idx] / (float)c;
}

// ---------------- FC head ----------------
__global__ void k_fc1(const float* __restrict__ rep, const u16* __restrict__ W,
                      const u16* __restrict__ bias, float* __restrict__ out) {
  __shared__ float a[128];
  int g = blockIdx.x, t = threadIdx.x;
  if (t < 128) a[t] = rep[g * 128 + t];
  __syncthreads();
  float a0 = 0, a1 = 0, a2 = 0, a3 = 0;
  for (int k = 0; k < 128; ++k) {
    float r = a[k];
    const u16* w = W + k * 1024 + t;
    a0 += r * b2f(w[0]);
    a1 += r * b2f(w[256]);
    a2 += r * b2f(w[512]);
    a3 += r * b2f(w[768]);
  }
  out[g * 1024 + t]       = fmaxf(a0 + b2f(bias[t]), 0.f);
  out[g * 1024 + t + 256] = fmaxf(a1 + b2f(bias[t + 256]), 0.f);
  out[g * 1024 + t + 512] = fmaxf(a2 + b2f(bias[t + 512]), 0.f);
  out[g * 1024 + t + 768] = fmaxf(a3 + b2f(bias[t + 768]), 0.f);
}

__global__ void k_fc2(const float* __restrict__ z, const u16* __restrict__ W,
                      const u16* __restrict__ bias, float* __restrict__ out) {
  __shared__ float a[1024];
  int g = blockIdx.x, t = threadIdx.x;
  for (int i = t; i < 1024; i += 256) a[i] = z[g * 1024 + i];
  __syncthreads();
  float a0 = 0, a1 = 0, a2 = 0, a3 = 0;
  for (int k = 0; k < 1024; ++k) {
    float r = a[k];
    const u16* w = W + k * 1024 + t;
    a0 += r * b2f(w[0]);
    a1 += r * b2f(w[256]);
    a2 += r * b2f(w[512]);
    a3 += r * b2f(w[768]);
  }
  out[g * 1024 + t]       = fmaxf(a0 + b2f(bias[t]), 0.f);
  out[g * 1024 + t + 256] = fmaxf(a1 + b2f(bias[t + 256]), 0.f);
  out[g * 1024 + t + 512] = fmaxf(a2 + b2f(bias[t + 512]), 0.f);
  out[g * 1024 + t + 768] = fmaxf(a3 + b2f(bias[t + 768]), 0.f);
}

__global__ void k_fc3(const float* __restrict__ z, const u16* __restrict__ W,
                      const u16* __restrict__ bias, float* __restrict__ out) {
  __shared__ float a[1024];
  int g = blockIdx.x, t = threadIdx.x;
  for (int i = t; i < 1024; i += 256) a[i] = z[g * 1024 + i];
  __syncthreads();
  float a0 = 0, a1 = 0;
  for (int k = 0; k < 1024; ++k) {
    float r = a[k];
    const u16* w = W + k * 512 + t;
    a0 += r * b2f(w[0]);
    a1 += r * b2f(w[256]);
  }
  out[g * 512 + t]       = fmaxf(a0 + b2f(bias[t]), 0.f);
  out[g * 512 + t + 256] = fmaxf(a1 + b2f(bias[t + 256]), 0.f);
}

__global__ void k_fc4(const float* __restrict__ z, const u16* __restrict__ W,
                      const u16* __restrict__ bias, void* __restrict__ out,
                      const int* __restrict__ flag) {
  int g = blockIdx.x, lane = threadIdx.x;  // 64 threads
  float acc = 0.f;
  for (int k = lane; k < 512; k += 64) acc += z[g * 512 + k] * b2f(W[k]);
  for (int off = 32; off > 0; off >>= 1) acc += __shfl_down(acc, off);
  if (lane == 0) {
    float r = acc + b2f(bias[0]);
    if (flag[0]) ((float*)out)[g] = r;
    else ((u16*)out)[g] = f2b(r);
  }
}

extern "C" void kernel_launch(void* const* d_in, const int* in_sizes, int n_in,
                              void* d_out, int out_size, void* d_ws, size_t ws_size,
                              hipStream_t stream) {
  const int* x     = (const int*)d_in[0];
  const int* ei    = (const int*)d_in[1];
  const int* eattr = (const int*)d_in[2];
  const int* batch = (const int*)d_in[3];

  char* ws = (char*)d_ws;
  size_t off = 0;
  auto alloc = [&](size_t bytes) -> void* {
    void* p = ws + off;
    off += (bytes + 255) & ~(size_t)255;
    return p;
  };
  int* flag = (int*)alloc(256);
  u16* cvt[23];
  CvtArgs ca;
  ca.cum[0] = 0;
  for (int i = 4; i <= 22; ++i) {
    cvt[i] = (u16*)alloc((size_t)in_sizes[i] * 2);
    ca.src[i - 4] = d_in[i];
    ca.dst[i - 4] = cvt[i];
    ca.cum[i - 3] = ca.cum[i - 4] + in_sizes[i];
  }

  u16*   h      = (u16*)  alloc((size_t)NN * 128 * 2);   // 12.8 MB
  u16*   amat   = (u16*)  alloc((size_t)NN * 128 * 2);   // 12.8 MB (aliases hpre)
  u16*   z0     = (u16*)  alloc((size_t)NN * 256 * 2);   // 25.6 MB
  int*   deg    = (int*)  alloc((size_t)NN * 4);
  int*   cursor = (int*)  alloc((size_t)NN * 4);
  int*   rowp   = (int*)  alloc((size_t)(NN + 1) * 4);
  uint2* epack  = (uint2*)alloc((size_t)EE * 8);         // 4.8 MB
  float* bnbuf  = (float*)alloc(768 * 4);
  float* bnstat = (float*)alloc(1152 * 4);
  float* rep    = (float*)alloc((size_t)GG * 128 * 4);
  int*   gstart = (int*)  alloc((size_t)GG * 4);
  int*   gend   = (int*)  alloc((size_t)GG * 4);
  float* fz1    = (float*)alloc((size_t)GG * 1024 * 4);
  float* fz2    = (float*)alloc((size_t)GG * 1024 * 4);
  float* fz3    = (float*)alloc((size_t)GG * 512 * 4);
  (void)ws_size; (void)n_in; (void)out_size;

  u16* hpre = amat;  // disjoint lifetimes

  float* bn1sum = bnbuf;
  float* bn1sq  = bnbuf + 256;
  float* bn2sum = bnbuf + 512;
  float* bn2sq  = bnbuf + 640;
  float* mean1  = bnstat;
  float* rsg1   = bnstat + 256;
  float* bb1    = bnstat + 512;
  float* mean2  = bnstat + 768;
  float* rsg2   = bnstat + 896;
  float* bb2    = bnstat + 1024;

  k_detect<<<1, 256, 0, stream>>>((const u32*)d_in[4], flag);
  {
    int total = ca.cum[19];
    k_cvt_all<<<(total + 255) / 256, 256, 0, stream>>>(ca, flag);
  }
  const u16 *aembc = cvt[4], *bembc = cvt[5], *epsc = cvt[6], *w1c = cvt[7],
            *b1c = cvt[8], *g1c = cvt[9], *be1c = cvt[10], *w2c = cvt[11],
            *b2c = cvt[12], *bngc = cvt[13], *bnbc = cvt[14], *fw1 = cvt[15],
            *fb1 = cvt[16], *fw2 = cvt[17], *fb2 = cvt[18], *fw3 = cvt[19],
            *fb3 = cvt[20], *fw4 = cvt[21], *fb4 = cvt[22];

  hipMemsetAsync(deg, 0, (size_t)NN * 4, stream);
  hipMemsetAsync(rep, 0, (size_t)GG * 128 * 4, stream);
  hipMemsetAsync(gstart, 0x7F, (size_t)GG * 4, stream);
  hipMemsetAsync(gend, 0xFF, (size_t)GG * 4, stream);
  hipMemsetAsync(bnbuf, 0, 768 * 4, stream);
  k_deg<<<(EE + 255) / 256, 256, 0, stream>>>(ei, deg);
  k_scan<<<1, 1024, 0, stream>>>(deg, rowp, cursor, NN);
  k_fill<<<(EE + 255) / 256, 256, 0, stream>>>(ei, eattr, cursor, epack);
  k_gb<<<(NN + 255) / 256, 256, 0, stream>>>(batch, gstart, gend);
  k_atom<<<(NN * 64 + 255) / 256, 256, 0, stream>>>(x, aembc, h);
  k_poolseg<<<GG * 4, 128, 0, stream>>>(h, gstart, gend, rep);

  const int gx = (NN + 127) / 128;  // 391
  for (int l = 0; l < LL; ++l) {
    k_pull<<<(NN + 3) / 4, 256, 0, stream>>>(h, rowp, epack,
                                             bembc + (size_t)l * 3 * 128 * 128, epsc, l, amat);
    dim3 grid1(gx, 2);
    k_gemm1<<<grid1, 256, 0, stream>>>(amat, w1c, b1c, z0, bn1sum, bn1sq);
    k_bnfin<<<1, 256, 0, stream>>>(bn1sum, bn1sq, g1c, be1c, mean1, rsg1, bb1);
    k_gemm2<<<gx, 256, 0, stream>>>(z0, mean1, rsg1, bb1, w2c, b2c, hpre, bn2sum, bn2sq);
    k_bnfin<<<1, 128, 0, stream>>>(bn2sum, bn2sq, bngc + l * 128, bnbc + l * 128,
                                   mean2, rsg2, bb2);
    k_bnapply<<<(NN * 128) / 1024, 256, 0, stream>>>(hpre, mean2, rsg2, bb2, h,
                                                     (l < LL - 1) ? 1 : 0);
    k_poolseg<<<GG * 4, 128, 0, stream>>>(h, gstart, gend, rep);
  }

  k_rep<<<(GG * 128) / 256, 256, 0, stream>>>(rep, gstart, gend);
  k_fc1<<<GG, 256, 0, stream>>>(rep, fw1, fb1, fz1);
  k_fc2<<<GG, 256, 0, stream>>>(fz1, fw2, fb2, fz2);
  k_fc3<<<GG, 256, 0, stream>>>(fz2, fw3, fb3, fz3);
  k_fc4<<<GG, 64, 0, stream>>>(fz3, fw4, fb4, d_out, flag);
}

// Round 6
// 1130.292 us; speedup vs baseline: 2.0884x; 1.1559x over previous
//
#include <hip/hip_runtime.h>

typedef unsigned short u16;
typedef unsigned int u32;
typedef __bf16 bf16x8 __attribute__((ext_vector_type(8)));
typedef float f32x4 __attribute__((ext_vector_type(4)));

#define NN 50000
#define EE 600000
#define GG 256
#define LL 5
#define NB 196  // ceil(NN/256)

__device__ __forceinline__ float b2f(u16 u) {
  unsigned int v = ((unsigned int)u) << 16;
  return __builtin_bit_cast(float, v);
}
__device__ __forceinline__ u16 f2b(float f) {
  unsigned int u = __builtin_bit_cast(unsigned int, f);
  u += 0x7FFFu + ((u >> 16) & 1u);
  return (u16)(u >> 16);
}

// ---------- dtype detect: flag=1 means floating inputs are fp32 ----------
__global__ void k_detect(const u32* __restrict__ w, int* __restrict__ flag) {
  __shared__ int sh[256];
  u32 v = w[threadIdx.x];
  u32 lo = v & 0xFFFFu;
  u32 e = (lo >> 7) & 0xFFu;
  sh[threadIdx.x] = (e >= 0x60u && e <= 0x7Fu) ? 1 : 0;
  __syncthreads();
  for (int s = 128; s > 0; s >>= 1) {
    if (threadIdx.x < (unsigned)s) sh[threadIdx.x] += sh[threadIdx.x + s];
    __syncthreads();
  }
  if (threadIdx.x == 0) flag[0] = (sh[0] < 128) ? 1 : 0;
}

struct CvtArgs {
  const void* src[19];
  u16* dst[19];
  int cum[20];
};

__global__ void k_cvt_all(CvtArgs a, const int* __restrict__ flag) {
  int t = blockIdx.x * 256 + threadIdx.x;
  if (t >= a.cum[19]) return;
  int i = 0;
  while (t >= a.cum[i + 1]) ++i;
  int j = t - a.cum[i];
  if (flag[0]) a.dst[i][j] = f2b(((const float*)a.src[i])[j]);
  else a.dst[i][j] = ((const u16*)a.src[i])[j];
}

// ---------- weight transpose: W1T[n][k]=W1[k][n] (256x128), W2T (128x256) ----------
__global__ void k_wt(const u16* __restrict__ w1, const u16* __restrict__ w2,
                     u16* __restrict__ w1t, u16* __restrict__ w2t) {
  int idx = blockIdx.x * 256 + threadIdx.x;
  if (idx < 32768) {
    int n = idx >> 7, k = idx & 127;     // n<256, k<128
    w1t[idx] = w1[k * 256 + n];
  } else {
    int r = idx - 32768;
    int n = r >> 8, k = r & 255;         // n<128, k<256
    w2t[r] = w2[k * 128 + n];
  }
}

// ---------------- CSR build ----------------
__global__ void k_deg(const int* __restrict__ ei, int* __restrict__ deg) {
  int e = blockIdx.x * 256 + threadIdx.x;
  if (e < EE) atomicAdd(&deg[ei[EE + e]], 1);
}

// 3-phase parallel exclusive scan over deg[NN]
__global__ void k_scan1(const int* __restrict__ deg, int* __restrict__ rowp,
                        int* __restrict__ bsum) {
  __shared__ int sh[256];
  int i = blockIdx.x * 256 + threadIdx.x;
  int v = (i < NN) ? deg[i] : 0;
  sh[threadIdx.x] = v;
  __syncthreads();
  for (int s = 1; s < 256; s <<= 1) {
    int t = (threadIdx.x >= (unsigned)s) ? sh[threadIdx.x - s] : 0;
    __syncthreads();
    sh[threadIdx.x] += t;
    __syncthreads();
  }
  if (i < NN) rowp[i] = sh[threadIdx.x] - v;  // chunk-local exclusive
  if (threadIdx.x == 255) bsum[blockIdx.x] = sh[255];
}

__global__ void k_scan2(int* __restrict__ bsum, int* __restrict__ boff) {
  __shared__ int sh[256];
  int v = (threadIdx.x < NB) ? bsum[threadIdx.x] : 0;
  sh[threadIdx.x] = v;
  __syncthreads();
  for (int s = 1; s < 256; s <<= 1) {
    int t = (threadIdx.x >= (unsigned)s) ? sh[threadIdx.x - s] : 0;
    __syncthreads();
    sh[threadIdx.x] += t;
    __syncthreads();
  }
  if (threadIdx.x < NB) boff[threadIdx.x] = sh[threadIdx.x] - v;
}

__global__ void k_scan3(int* __restrict__ rowp, const int* __restrict__ boff,
                        int* __restrict__ cursor) {
  int i = blockIdx.x * 256 + threadIdx.x;
  if (i < NN) {
    int r = rowp[i] + boff[blockIdx.x];
    rowp[i] = r;
    cursor[i] = r;
  }
  if (i == 0) rowp[NN] = EE;
}

// fill CSR; pack edge as (src:16 | a0:7<<16 | a1:7<<23, a2)
__global__ void k_fill(const int* __restrict__ ei, const int* __restrict__ eattr,
                       int* __restrict__ cursor, uint2* __restrict__ epack) {
  int e = blockIdx.x * 256 + threadIdx.x;
  if (e < EE) {
    int d = ei[EE + e];
    int pos = atomicAdd(&cursor[d], 1);
    u32 src = (u32)ei[e];
    u32 a0 = (u32)eattr[e * 3], a1 = (u32)eattr[e * 3 + 1], a2 = (u32)eattr[e * 3 + 2];
    epack[pos] = make_uint2(src | (a0 << 16) | (a1 << 23), a2);
  }
}

// ---------------- graph segment bounds (batch is sorted) ----------------
__global__ void k_gb(const int* __restrict__ batch, int* __restrict__ gstart,
                     int* __restrict__ gend) {
  int n = blockIdx.x * 256 + threadIdx.x;
  if (n < NN) {
    int b = batch[n];
    atomicMin(&gstart[b], n);
    atomicMax(&gend[b], n);
  }
}

// ---------------- atom embed (2 feats/thread) ----------------
__global__ void k_atom(const int* __restrict__ x, const u16* __restrict__ aemb,
                       u16* __restrict__ h) {
  int idx = blockIdx.x * 256 + threadIdx.x;  // over NN*64
  if (idx >= NN * 64) return;
  int n = idx >> 6, f2 = (idx & 63) << 1;
  float a0 = 0.f, a1 = 0.f;
#pragma unroll
  for (int j = 0; j < 9; ++j) {
    int xv = x[n * 9 + j];
    u32 v = *(const u32*)(aemb + (j * 128 + xv) * 128 + f2);
    a0 += b2f((u16)v);
    a1 += b2f((u16)(v >> 16));
  }
  u32 o = (u32)f2b(a0) | ((u32)f2b(a1) << 16);
  *(u32*)(h + n * 128 + f2) = o;
}

// ------- pull: wave per node, 2 feats/lane, 4-edge groups for MLP -------
__global__ __launch_bounds__(256)
void k_pull(const u16* __restrict__ h, const int* __restrict__ rowp,
            const uint2* __restrict__ epack, const u16* __restrict__ bond,
            const u16* __restrict__ epsv, int layer, u16* __restrict__ amat) {
  const int lane = threadIdx.x & 63;
  const int node = blockIdx.x * 4 + (threadIdx.x >> 6);
  const int p0 = rowp[node], p1 = rowp[node + 1];
  const int lo = lane << 1;
  const u16* bondB = bond + 16384;
  const u16* bondC = bond + 32768;
  float acc0 = 0.f, acc1 = 0.f;
  int p = p0;
  for (; p + 4 <= p1; p += 4) {
    uint2 e0 = epack[p], e1 = epack[p + 1], e2 = epack[p + 2], e3 = epack[p + 3];
    u32 h0 = *(const u32*)(h + (size_t)(e0.x & 0xFFFFu) * 128 + lo);
    u32 h1 = *(const u32*)(h + (size_t)(e1.x & 0xFFFFu) * 128 + lo);
    u32 h2 = *(const u32*)(h + (size_t)(e2.x & 0xFFFFu) * 128 + lo);
    u32 h3 = *(const u32*)(h + (size_t)(e3.x & 0xFFFFu) * 128 + lo);
    u32 a0 = *(const u32*)(bond + ((e0.x >> 16) & 0x7Fu) * 128 + lo);
    u32 a1 = *(const u32*)(bond + ((e1.x >> 16) & 0x7Fu) * 128 + lo);
    u32 a2 = *(const u32*)(bond + ((e2.x >> 16) & 0x7Fu) * 128 + lo);
    u32 a3 = *(const u32*)(bond + ((e3.x >> 16) & 0x7Fu) * 128 + lo);
    u32 b0 = *(const u32*)(bondB + ((e0.x >> 23) & 0x7Fu) * 128 + lo);
    u32 b1 = *(const u32*)(bondB + ((e1.x >> 23) & 0x7Fu) * 128 + lo);
    u32 b2 = *(const u32*)(bondB + ((e2.x >> 23) & 0x7Fu) * 128 + lo);
    u32 b3 = *(const u32*)(bondB + ((e3.x >> 23) & 0x7Fu) * 128 + lo);
    u32 c0 = *(const u32*)(bondC + e0.y * 128 + lo);
    u32 c1 = *(const u32*)(bondC + e1.y * 128 + lo);
    u32 c2 = *(const u32*)(bondC + e2.y * 128 + lo);
    u32 c3 = *(const u32*)(bondC + e3.y * 128 + lo);
    acc0 += fmaxf(b2f((u16)h0) + b2f((u16)a0) + b2f((u16)b0) + b2f((u16)c0), 0.f);
    acc1 += fmaxf(b2f((u16)(h0 >> 16)) + b2f((u16)(a0 >> 16)) + b2f((u16)(b0 >> 16)) + b2f((u16)(c0 >> 16)), 0.f);
    acc0 += fmaxf(b2f((u16)h1) + b2f((u16)a1) + b2f((u16)b1) + b2f((u16)c1), 0.f);
    acc1 += fmaxf(b2f((u16)(h1 >> 16)) + b2f((u16)(a1 >> 16)) + b2f((u16)(b1 >> 16)) + b2f((u16)(c1 >> 16)), 0.f);
    acc0 += fmaxf(b2f((u16)h2) + b2f((u16)a2) + b2f((u16)b2) + b2f((u16)c2), 0.f);
    acc1 += fmaxf(b2f((u16)(h2 >> 16)) + b2f((u16)(a2 >> 16)) + b2f((u16)(b2 >> 16)) + b2f((u16)(c2 >> 16)), 0.f);
    acc0 += fmaxf(b2f((u16)h3) + b2f((u16)a3) + b2f((u16)b3) + b2f((u16)c3), 0.f);
    acc1 += fmaxf(b2f((u16)(h3 >> 16)) + b2f((u16)(a3 >> 16)) + b2f((u16)(b3 >> 16)) + b2f((u16)(c3 >> 16)), 0.f);
  }
  for (; p < p1; ++p) {
    uint2 e0 = epack[p];
    u32 h0 = *(const u32*)(h + (size_t)(e0.x & 0xFFFFu) * 128 + lo);
    u32 a0 = *(const u32*)(bond + ((e0.x >> 16) & 0x7Fu) * 128 + lo);
    u32 b0 = *(const u32*)(bondB + ((e0.x >> 23) & 0x7Fu) * 128 + lo);
    u32 c0 = *(const u32*)(bondC + e0.y * 128 + lo);
    acc0 += fmaxf(b2f((u16)h0) + b2f((u16)a0) + b2f((u16)b0) + b2f((u16)c0), 0.f);
    acc1 += fmaxf(b2f((u16)(h0 >> 16)) + b2f((u16)(a0 >> 16)) + b2f((u16)(b0 >> 16)) + b2f((u16)(c0 >> 16)), 0.f);
  }
  float epsf = 1.0f + b2f(epsv[layer]);
  u32 own = *(const u32*)(h + (size_t)node * 128 + lo);
  u32 o = (u32)f2b(epsf * b2f((u16)own) + acc0) |
          ((u32)f2b(epsf * b2f((u16)(own >> 16)) + acc1) << 16);
  *(u32*)(amat + (size_t)node * 128 + lo) = o;
}

// ---- GEMM1: z0 = amat @ W1 + b1 (bf16 out) + BN1 stats. Direct-global MFMA, no LDS staging. ----
__global__ __launch_bounds__(256)
void k_gemm1(const u16* __restrict__ amat, const u16* __restrict__ w1t,
             const u16* __restrict__ b1, u16* __restrict__ z0,
             float* __restrict__ bnsum, float* __restrict__ bnsq) {
  __shared__ float colAcc[256];
  const int tid = threadIdx.x;
  const int r0 = blockIdx.x * 128;
  const int nc = blockIdx.y * 128;
  const int w = tid >> 6, lane = tid & 63, l15 = lane & 15, q = lane >> 4;
  const int wr = (w & 1) * 64, wc = (w >> 1) * 64;
  f32x4 acc[4][4];
#pragma unroll
  for (int i = 0; i < 4; ++i)
#pragma unroll
    for (int j = 0; j < 4; ++j) acc[i][j] = {0.f, 0.f, 0.f, 0.f};

  int arow[4], brow[4];
#pragma unroll
  for (int i = 0; i < 4; ++i) {
    int r = r0 + wr + i * 16 + l15;
    arow[i] = (r < NN) ? r : (NN - 1);     // clamp: OOB rows discarded in epilogue
    brow[i] = nc + wc + i * 16 + l15;
  }
#pragma unroll
  for (int kb = 0; kb < 4; ++kb) {
    const int kf = kb * 32 + q * 8;
    bf16x8 a[4], b[4];
#pragma unroll
    for (int i = 0; i < 4; ++i) a[i] = *(const bf16x8*)(amat + (size_t)arow[i] * 128 + kf);
#pragma unroll
    for (int j = 0; j < 4; ++j) b[j] = *(const bf16x8*)(w1t + (size_t)brow[j] * 128 + kf);
#pragma unroll
    for (int i = 0; i < 4; ++i)
#pragma unroll
      for (int j = 0; j < 4; ++j)
        acc[i][j] = __builtin_amdgcn_mfma_f32_16x16x32_bf16(a[i], b[j], acc[i][j], 0, 0, 0);
  }
  colAcc[tid] = 0.f;
  __syncthreads();
#pragma unroll
  for (int j = 0; j < 4; ++j) {
    const int c = wc + j * 16 + l15;
    const float bias = b2f(b1[nc + c]);
    float ls = 0.f, lsq = 0.f;
#pragma unroll
    for (int i = 0; i < 4; ++i) {
      const int gr = r0 + wr + i * 16 + q * 4;
#pragma unroll
      for (int rg = 0; rg < 4; ++rg) {
        if (gr + rg < NN) {
          const float v = acc[i][j][rg] + bias;
          z0[(gr + rg) * 256 + nc + c] = f2b(v);
          ls += v;
          lsq += v * v;
        }
      }
    }
    atomicAdd(&colAcc[c], ls);
    atomicAdd(&colAcc[128 + c], lsq);
  }
  __syncthreads();
  if (tid < 128) {
    atomicAdd(&bnsum[nc + tid], colAcc[tid]);
    atomicAdd(&bnsq[nc + tid], colAcc[128 + tid]);
  }
}

// bnfin: fold BN into c1 = rs*g, c0 = beta - m*c1; zero stats for next layer
__global__ void k_bnfin(float* __restrict__ bnsum, float* __restrict__ bnsq,
                        const u16* __restrict__ g, const u16* __restrict__ b,
                        float* __restrict__ c1, float* __restrict__ c0) {
  int t = threadIdx.x;
  float s = bnsum[t], q = bnsq[t];
  bnsum[t] = 0.f;
  bnsq[t] = 0.f;
  float m = s * (1.0f / NN);
  float var = q * (1.0f / NN) - m * m;
  float rs = rsqrtf(var + 1e-5f);
  float cc1 = rs * b2f(g[t]);
  c1[t] = cc1;
  c0[t] = b2f(b[t]) - m * cc1;
}

// ---- GEMM2: hpre = relu(z0*c1+c0) @ W2 + b2 (bf16 out) + BN2 stats. BN1 inline on A-frags. ----
__global__ __launch_bounds__(256)
void k_gemm2(const u16* __restrict__ z0, const float* __restrict__ c1,
             const float* __restrict__ c0, const u16* __restrict__ w2t,
             const u16* __restrict__ b2, u16* __restrict__ hpre,
             float* __restrict__ bnsum, float* __restrict__ bnsq) {
  __shared__ float colAcc[256];
  const int tid = threadIdx.x;
  const int r0 = blockIdx.x * 128;
  const int w = tid >> 6, lane = tid & 63, l15 = lane & 15, q = lane >> 4;
  const int wr = (w & 1) * 64, wc = (w >> 1) * 64;
  f32x4 acc[4][4];
#pragma unroll
  for (int i = 0; i < 4; ++i)
#pragma unroll
    for (int j = 0; j < 4; ++j) acc[i][j] = {0.f, 0.f, 0.f, 0.f};

  int arow[4], brow[4];
#pragma unroll
  for (int i = 0; i < 4; ++i) {
    int r = r0 + wr + i * 16 + l15;
    arow[i] = (r < NN) ? r : (NN - 1);
    brow[i] = wc + i * 16 + l15;
  }
#pragma unroll
  for (int kb = 0; kb < 8; ++kb) {
    const int kf = kb * 32 + q * 8;
    bf16x8 a[4], b[4];
#pragma unroll
    for (int i = 0; i < 4; ++i) a[i] = *(const bf16x8*)(z0 + (size_t)arow[i] * 256 + kf);
#pragma unroll
    for (int j = 0; j < 4; ++j) b[j] = *(const bf16x8*)(w2t + (size_t)brow[j] * 256 + kf);
    // inline BN1 + relu on A fragments: a = relu(a*c1+c0), per k-column
    float c1v[8], c0v[8];
#pragma unroll
    for (int e = 0; e < 8; ++e) { c1v[e] = c1[kf + e]; c0v[e] = c0[kf + e]; }
#pragma unroll
    for (int i = 0; i < 4; ++i) {
      bf16x8 t = a[i];
#pragma unroll
      for (int e = 0; e < 8; ++e)
        t[e] = (__bf16)fmaxf((float)t[e] * c1v[e] + c0v[e], 0.f);
      a[i] = t;
    }
#pragma unroll
    for (int i = 0; i < 4; ++i)
#pragma unroll
      for (int j = 0; j < 4; ++j)
        acc[i][j] = __builtin_amdgcn_mfma_f32_16x16x32_bf16(a[i], b[j], acc[i][j], 0, 0, 0);
  }
  colAcc[tid] = 0.f;
  __syncthreads();
#pragma unroll
  for (int j = 0; j < 4; ++j) {
    const int c = wc + j * 16 + l15;
    const float bias = b2f(b2[c]);
    float ls = 0.f, lsq = 0.f;
#pragma unroll
    for (int i = 0; i < 4; ++i) {
      const int gr = r0 + wr + i * 16 + q * 4;
#pragma unroll
      for (int rg = 0; rg < 4; ++rg) {
        if (gr + rg < NN) {
          const float v = acc[i][j][rg] + bias;
          hpre[(gr + rg) * 128 + c] = f2b(v);
          ls += v;
          lsq += v * v;
        }
      }
    }
    atomicAdd(&colAcc[c], ls);
    atomicAdd(&colAcc[128 + c], lsq);
  }
  __syncthreads();
  if (tid < 128) {
    atomicAdd(&bnsum[tid], colAcc[tid]);
    atomicAdd(&bnsq[tid], colAcc[128 + tid]);
  }
}

// ------- BN2 apply (folded) + relu + write h (vectorized x4) -------
__global__ void k_bnapply(const u16* __restrict__ hpre, const float* __restrict__ c1,
                          const float* __restrict__ c0, u16* __restrict__ h, int dorelu) {
  int idx4 = (blockIdx.x * 256 + threadIdx.x) * 4;
  if (idx4 >= NN * 128) return;
  int f = idx4 & 127;
  const ushort4 hv = *(const ushort4*)(hpre + idx4);
  const float4 rv = *(const float4*)(c1 + f);
  const float4 bv = *(const float4*)(c0 + f);
  float v0 = b2f(hv.x) * rv.x + bv.x;
  float v1 = b2f(hv.y) * rv.y + bv.y;
  float v2 = b2f(hv.z) * rv.z + bv.z;
  float v3 = b2f(hv.w) * rv.w + bv.w;
  if (dorelu) {
    v0 = fmaxf(v0, 0.f); v1 = fmaxf(v1, 0.f);
    v2 = fmaxf(v2, 0.f); v3 = fmaxf(v3, 0.f);
  }
  ushort4 ov;
  ov.x = f2b(v0); ov.y = f2b(v1); ov.z = f2b(v2); ov.w = f2b(v3);
  *(ushort4*)(h + idx4) = ov;
}

// ------- segment pooling, 4 blocks per graph, atomic fp32 into rep -------
__global__ void k_poolseg(const u16* __restrict__ h, const int* __restrict__ gstart,
                          const int* __restrict__ gend, float* __restrict__ rep) {
  int g = blockIdx.x >> 2, part = blockIdx.x & 3, f = threadIdx.x;  // 128 threads
  int r0 = gstart[g], r1 = gend[g] + 1;
  int len = r1 - r0;
  if (len <= 0) return;
  int chunk = (len + 3) >> 2;
  int s = r0 + part * chunk;
  int e = s + chunk; if (e > r1) e = r1;
  float acc = 0.f;
  for (int r = s; r < e; ++r) acc += b2f(h[r * 128 + f]);
  if (s < e) atomicAdd(&rep[g * 128 + f], acc);
}

__global__ void k_rep(float* __restrict__ rep, const int* __restrict__ gstart,
                      const int* __restrict__ gend) {
  int idx = blockIdx.x * 256 + threadIdx.x;  // GG*128
  int g = idx >> 7;
  int c = gend[g] - gstart[g] + 1;
  if (c < 1) c = 1;
  rep[idx] = rep[idx] / (float)c;
}

// ---------------- FC head ----------------
__global__ void k_fc1(const float* __restrict__ rep, const u16* __restrict__ W,
                      const u16* __restrict__ bias, float* __restrict__ out) {
  __shared__ float a[128];
  int g = blockIdx.x, t = threadIdx.x;
  if (t < 128) a[t] = rep[g * 128 + t];
  __syncthreads();
  float a0 = 0, a1 = 0, a2 = 0, a3 = 0;
  for (int k = 0; k < 128; ++k) {
    float r = a[k];
    const u16* w = W + k * 1024 + t;
    a0 += r * b2f(w[0]);
    a1 += r * b2f(w[256]);
    a2 += r * b2f(w[512]);
    a3 += r * b2f(w[768]);
  }
  out[g * 1024 + t]       = fmaxf(a0 + b2f(bias[t]), 0.f);
  out[g * 1024 + t + 256] = fmaxf(a1 + b2f(bias[t + 256]), 0.f);
  out[g * 1024 + t + 512] = fmaxf(a2 + b2f(bias[t + 512]), 0.f);
  out[g * 1024 + t + 768] = fmaxf(a3 + b2f(bias[t + 768]), 0.f);
}

__global__ void k_fc2(const float* __restrict__ z, const u16* __restrict__ W,
                      const u16* __restrict__ bias, float* __restrict__ out) {
  __shared__ float a[1024];
  int g = blockIdx.x, t = threadIdx.x;
  for (int i = t; i < 1024; i += 256) a[i] = z[g * 1024 + i];
  __syncthreads();
  float a0 = 0, a1 = 0, a2 = 0, a3 = 0;
  for (int k = 0; k < 1024; ++k) {
    float r = a[k];
    const u16* w = W + k * 1024 + t;
    a0 += r * b2f(w[0]);
    a1 += r * b2f(w[256]);
    a2 += r * b2f(w[512]);
    a3 += r * b2f(w[768]);
  }
  out[g * 1024 + t]       = fmaxf(a0 + b2f(bias[t]), 0.f);
  out[g * 1024 + t + 256] = fmaxf(a1 + b2f(bias[t + 256]), 0.f);
  out[g * 1024 + t + 512] = fmaxf(a2 + b2f(bias[t + 512]), 0.f);
  out[g * 1024 + t + 768] = fmaxf(a3 + b2f(bias[t + 768]), 0.f);
}

__global__ void k_fc3(const float* __restrict__ z, const u16* __restrict__ W,
                      const u16* __restrict__ bias, float* __restrict__ out) {
  __shared__ float a[1024];
  int g = blockIdx.x, t = threadIdx.x;
  for (int i = t; i < 1024; i += 256) a[i] = z[g * 1024 + i];
  __syncthreads();
  float a0 = 0, a1 = 0;
  for (int k = 0; k < 1024; ++k) {
    float r = a[k];
    const u16* w = W + k * 512 + t;
    a0 += r * b2f(w[0]);
    a1 += r * b2f(w[256]);
  }
  out[g * 512 + t]       = fmaxf(a0 + b2f(bias[t]), 0.f);
  out[g * 512 + t + 256] = fmaxf(a1 + b2f(bias[t + 256]), 0.f);
}

__global__ void k_fc4(const float* __restrict__ z, const u16* __restrict__ W,
                      const u16* __restrict__ bias, void* __restrict__ out,
                      const int* __restrict__ flag) {
  int g = blockIdx.x, lane = threadIdx.x;  // 64 threads
  float acc = 0.f;
  for (int k = lane; k < 512; k += 64) acc += z[g * 512 + k] * b2f(W[k]);
  for (int off = 32; off > 0; off >>= 1) acc += __shfl_down(acc, off);
  if (lane == 0) {
    float r = acc + b2f(bias[0]);
    if (flag[0]) ((float*)out)[g] = r;
    else ((u16*)out)[g] = f2b(r);
  }
}

extern "C" void kernel_launch(void* const* d_in, const int* in_sizes, int n_in,
                              void* d_out, int out_size, void* d_ws, size_t ws_size,
                              hipStream_t stream) {
  const int* x     = (const int*)d_in[0];
  const int* ei    = (const int*)d_in[1];
  const int* eattr = (const int*)d_in[2];
  const int* batch = (const int*)d_in[3];

  char* ws = (char*)d_ws;
  size_t off = 0;
  auto alloc = [&](size_t bytes) -> void* {
    void* p = ws + off;
    off += (bytes + 255) & ~(size_t)255;
    return p;
  };
  int* flag = (int*)alloc(256);
  u16* cvt[23];
  CvtArgs ca;
  ca.cum[0] = 0;
  for (int i = 4; i <= 22; ++i) {
    cvt[i] = (u16*)alloc((size_t)in_sizes[i] * 2);
    ca.src[i - 4] = d_in[i];
    ca.dst[i - 4] = cvt[i];
    ca.cum[i - 3] = ca.cum[i - 4] + in_sizes[i];
  }

  u16*   h      = (u16*)  alloc((size_t)NN * 128 * 2);   // 12.8 MB
  u16*   amat   = (u16*)  alloc((size_t)NN * 128 * 2);   // 12.8 MB (aliases hpre)
  u16*   z0     = (u16*)  alloc((size_t)NN * 256 * 2);   // 25.6 MB
  u16*   w1t    = (u16*)  alloc(32768 * 2);
  u16*   w2t    = (u16*)  alloc(32768 * 2);
  int*   deg    = (int*)  alloc((size_t)NN * 4);
  int*   cursor = (int*)  alloc((size_t)NN * 4);
  int*   rowp   = (int*)  alloc((size_t)(NN + 1) * 4);
  int*   bsum   = (int*)  alloc((size_t)NB * 4);
  int*   boff   = (int*)  alloc((size_t)NB * 4);
  uint2* epack  = (uint2*)alloc((size_t)EE * 8);         // 4.8 MB
  float* bnbuf  = (float*)alloc(768 * 4);
  float* bnstat = (float*)alloc(1152 * 4);
  float* rep    = (float*)alloc((size_t)GG * 128 * 4);
  int*   gstart = (int*)  alloc((size_t)GG * 4);
  int*   gend   = (int*)  alloc((size_t)GG * 4);
  float* fz1    = (float*)alloc((size_t)GG * 1024 * 4);
  float* fz2    = (float*)alloc((size_t)GG * 1024 * 4);
  float* fz3    = (float*)alloc((size_t)GG * 512 * 4);
  (void)ws_size; (void)n_in; (void)out_size;

  u16* hpre = amat;  // disjoint lifetimes

  float* bn1sum = bnbuf;
  float* bn1sq  = bnbuf + 256;
  float* bn2sum = bnbuf + 512;
  float* bn2sq  = bnbuf + 640;
  float* c1a    = bnstat;          // BN1 folded scale (256)
  float* c0a    = bnstat + 256;    // BN1 folded shift (256)
  float* c1b    = bnstat + 512;    // BN2 folded scale (128)
  float* c0b    = bnstat + 640;    // BN2 folded shift (128)

  k_detect<<<1, 256, 0, stream>>>((const u32*)d_in[4], flag);
  {
    int total = ca.cum[19];
    k_cvt_all<<<(total + 255) / 256, 256, 0, stream>>>(ca, flag);
  }
  const u16 *aembc = cvt[4], *bembc = cvt[5], *epsc = cvt[6], *w1c = cvt[7],
            *b1c = cvt[8], *g1c = cvt[9], *be1c = cvt[10], *w2c = cvt[11],
            *b2c = cvt[12], *bngc = cvt[13], *bnbc = cvt[14], *fw1 = cvt[15],
            *fb1 = cvt[16], *fw2 = cvt[17], *fb2 = cvt[18], *fw3 = cvt[19],
            *fb3 = cvt[20], *fw4 = cvt[21], *fb4 = cvt[22];

  k_wt<<<65536 / 256, 256, 0, stream>>>(w1c, w2c, w1t, w2t);

  hipMemsetAsync(deg, 0, (size_t)NN * 4, stream);
  hipMemsetAsync(rep, 0, (size_t)GG * 128 * 4, stream);
  hipMemsetAsync(gstart, 0x7F, (size_t)GG * 4, stream);
  hipMemsetAsync(gend, 0xFF, (size_t)GG * 4, stream);
  hipMemsetAsync(bnbuf, 0, 768 * 4, stream);
  k_deg<<<(EE + 255) / 256, 256, 0, stream>>>(ei, deg);
  k_scan1<<<NB, 256, 0, stream>>>(deg, rowp, bsum);
  k_scan2<<<1, 256, 0, stream>>>(bsum, boff);
  k_scan3<<<NB, 256, 0, stream>>>(rowp, boff, cursor);
  k_fill<<<(EE + 255) / 256, 256, 0, stream>>>(ei, eattr, cursor, epack);
  k_gb<<<(NN + 255) / 256, 256, 0, stream>>>(batch, gstart, gend);
  k_atom<<<(NN * 64 + 255) / 256, 256, 0, stream>>>(x, aembc, h);
  k_poolseg<<<GG * 4, 128, 0, stream>>>(h, gstart, gend, rep);

  const int gx = (NN + 127) / 128;  // 391
  for (int l = 0; l < LL; ++l) {
    k_pull<<<(NN + 3) / 4, 256, 0, stream>>>(h, rowp, epack,
                                             bembc + (size_t)l * 3 * 128 * 128, epsc, l, amat);
    dim3 grid1(gx, 2);
    k_gemm1<<<grid1, 256, 0, stream>>>(amat, w1t, b1c, z0, bn1sum, bn1sq);
    k_bnfin<<<1, 256, 0, stream>>>(bn1sum, bn1sq, g1c, be1c, c1a, c0a);
    k_gemm2<<<gx, 256, 0, stream>>>(z0, c1a, c0a, w2t, b2c, hpre, bn2sum, bn2sq);
    k_bnfin<<<1, 128, 0, stream>>>(bn2sum, bn2sq, bngc + l * 128, bnbc + l * 128,
                                   c1b, c0b);
    k_bnapply<<<(NN * 128) / 1024, 256, 0, stream>>>(hpre, c1b, c0b, h,
                                                     (l < LL - 1) ? 1 : 0);
    k_poolseg<<<GG * 4, 128, 0, stream>>>(h, gstart, gend, rep);
  }

  k_rep<<<(GG * 128) / 256, 256, 0, stream>>>(rep, gstart, gend);
  k_fc1<<<GG, 256, 0, stream>>>(rep, fw1, fb1, fz1);
  k_fc2<<<GG, 256, 0, stream>>>(fz1, fw2, fb2, fz2);
  k_fc3<<<GG, 256, 0, stream>>>(fz2, fw3, fb3, fz3);
  k_fc4<<<GG, 64, 0, stream>>>(fz3, fw4, fb4, d_out, flag);
}

// Round 7
// 1028.214 us; speedup vs baseline: 2.2957x; 1.0993x over previous
//
#include <hip/hip_runtime.h>

typedef unsigned short u16;
typedef unsigned int u32;
typedef __bf16 bf16x8 __attribute__((ext_vector_type(8)));
typedef float f32x4 __attribute__((ext_vector_type(4)));

#define NN 50000
#define EE 600000
#define GG 256
#define LL 5
#define NB 196  // ceil(NN/256)

__device__ __forceinline__ float b2f(u16 u) {
  unsigned int v = ((unsigned int)u) << 16;
  return __builtin_bit_cast(float, v);
}
__device__ __forceinline__ u16 f2b(float f) {
  unsigned int u = __builtin_bit_cast(unsigned int, f);
  u += 0x7FFFu + ((u >> 16) & 1u);
  return (u16)(u >> 16);
}

// ---------- dtype detect: flag=1 means floating inputs are fp32 ----------
__global__ void k_detect(const u32* __restrict__ w, int* __restrict__ flag) {
  __shared__ int sh[256];
  u32 v = w[threadIdx.x];
  u32 lo = v & 0xFFFFu;
  u32 e = (lo >> 7) & 0xFFu;
  sh[threadIdx.x] = (e >= 0x60u && e <= 0x7Fu) ? 1 : 0;
  __syncthreads();
  for (int s = 128; s > 0; s >>= 1) {
    if (threadIdx.x < (unsigned)s) sh[threadIdx.x] += sh[threadIdx.x + s];
    __syncthreads();
  }
  if (threadIdx.x == 0) flag[0] = (sh[0] < 128) ? 1 : 0;
}

struct CvtArgs {
  const void* src[19];
  u16* dst[19];
  int cum[20];
};

__global__ void k_cvt_all(CvtArgs a, const int* __restrict__ flag) {
  int t = blockIdx.x * 256 + threadIdx.x;
  if (t >= a.cum[19]) return;
  int i = 0;
  while (t >= a.cum[i + 1]) ++i;
  int j = t - a.cum[i];
  if (flag[0]) a.dst[i][j] = f2b(((const float*)a.src[i])[j]);
  else a.dst[i][j] = ((const u16*)a.src[i])[j];
}

// ---------- generic transpose: dst[n][k] = src[k][n], src is [K][N] ----------
__global__ void k_tr(const u16* __restrict__ src, u16* __restrict__ dst, int K, int N) {
  int idx = blockIdx.x * 256 + threadIdx.x;
  if (idx >= K * N) return;
  int n = idx / K, k = idx - n * K;
  dst[idx] = src[k * N + n];
}

// ---------------- CSR build ----------------
__global__ void k_deg(const int* __restrict__ ei, int* __restrict__ deg) {
  int e = blockIdx.x * 256 + threadIdx.x;
  if (e < EE) atomicAdd(&deg[ei[EE + e]], 1);
}

__global__ void k_scan1(const int* __restrict__ deg, int* __restrict__ rowp,
                        int* __restrict__ bsum) {
  __shared__ int sh[256];
  int i = blockIdx.x * 256 + threadIdx.x;
  int v = (i < NN) ? deg[i] : 0;
  sh[threadIdx.x] = v;
  __syncthreads();
  for (int s = 1; s < 256; s <<= 1) {
    int t = (threadIdx.x >= (unsigned)s) ? sh[threadIdx.x - s] : 0;
    __syncthreads();
    sh[threadIdx.x] += t;
    __syncthreads();
  }
  if (i < NN) rowp[i] = sh[threadIdx.x] - v;
  if (threadIdx.x == 255) bsum[blockIdx.x] = sh[255];
}

__global__ void k_scan2(int* __restrict__ bsum, int* __restrict__ boff) {
  __shared__ int sh[256];
  int v = (threadIdx.x < NB) ? bsum[threadIdx.x] : 0;
  sh[threadIdx.x] = v;
  __syncthreads();
  for (int s = 1; s < 256; s <<= 1) {
    int t = (threadIdx.x >= (unsigned)s) ? sh[threadIdx.x - s] : 0;
    __syncthreads();
    sh[threadIdx.x] += t;
    __syncthreads();
  }
  if (threadIdx.x < NB) boff[threadIdx.x] = sh[threadIdx.x] - v;
}

__global__ void k_scan3(int* __restrict__ rowp, const int* __restrict__ boff,
                        int* __restrict__ cursor) {
  int i = blockIdx.x * 256 + threadIdx.x;
  if (i < NN) {
    int r = rowp[i] + boff[blockIdx.x];
    rowp[i] = r;
    cursor[i] = r;
  }
  if (i == 0) rowp[NN] = EE;
}

__global__ void k_fill(const int* __restrict__ ei, const int* __restrict__ eattr,
                       int* __restrict__ cursor, uint2* __restrict__ epack) {
  int e = blockIdx.x * 256 + threadIdx.x;
  if (e < EE) {
    int d = ei[EE + e];
    int pos = atomicAdd(&cursor[d], 1);
    u32 src = (u32)ei[e];
    u32 a0 = (u32)eattr[e * 3], a1 = (u32)eattr[e * 3 + 1], a2 = (u32)eattr[e * 3 + 2];
    epack[pos] = make_uint2(src | (a0 << 16) | (a1 << 23), a2);
  }
}

__global__ void k_gb(const int* __restrict__ batch, int* __restrict__ gstart,
                     int* __restrict__ gend) {
  int n = blockIdx.x * 256 + threadIdx.x;
  if (n < NN) {
    int b = batch[n];
    atomicMin(&gstart[b], n);
    atomicMax(&gend[b], n);
  }
}

// ---------------- atom embed (2 feats/thread) ----------------
__global__ void k_atom(const int* __restrict__ x, const u16* __restrict__ aemb,
                       u16* __restrict__ h) {
  int idx = blockIdx.x * 256 + threadIdx.x;  // over NN*64
  if (idx >= NN * 64) return;
  int n = idx >> 6, f2 = (idx & 63) << 1;
  float a0 = 0.f, a1 = 0.f;
#pragma unroll
  for (int j = 0; j < 9; ++j) {
    int xv = x[n * 9 + j];
    u32 v = *(const u32*)(aemb + (j * 128 + xv) * 128 + f2);
    a0 += b2f((u16)v);
    a1 += b2f((u16)(v >> 16));
  }
  u32 o = (u32)f2b(a0) | ((u32)f2b(a1) << 16);
  *(u32*)(h + n * 128 + f2) = o;
}

// ------- pull: wave per node, 2 feats/lane, 4-edge groups for MLP -------
__global__ __launch_bounds__(256)
void k_pull(const u16* __restrict__ h, const int* __restrict__ rowp,
            const uint2* __restrict__ epack, const u16* __restrict__ bond,
            const u16* __restrict__ epsv, int layer, u16* __restrict__ amat) {
  const int lane = threadIdx.x & 63;
  const int node = blockIdx.x * 4 + (threadIdx.x >> 6);
  const int p0 = rowp[node], p1 = rowp[node + 1];
  const int lo = lane << 1;
  const u16* bondB = bond + 16384;
  const u16* bondC = bond + 32768;
  float acc0 = 0.f, acc1 = 0.f;
  int p = p0;
  for (; p + 4 <= p1; p += 4) {
    uint2 e0 = epack[p], e1 = epack[p + 1], e2 = epack[p + 2], e3 = epack[p + 3];
    u32 h0 = *(const u32*)(h + (size_t)(e0.x & 0xFFFFu) * 128 + lo);
    u32 h1 = *(const u32*)(h + (size_t)(e1.x & 0xFFFFu) * 128 + lo);
    u32 h2 = *(const u32*)(h + (size_t)(e2.x & 0xFFFFu) * 128 + lo);
    u32 h3 = *(const u32*)(h + (size_t)(e3.x & 0xFFFFu) * 128 + lo);
    u32 a0 = *(const u32*)(bond + ((e0.x >> 16) & 0x7Fu) * 128 + lo);
    u32 a1 = *(const u32*)(bond + ((e1.x >> 16) & 0x7Fu) * 128 + lo);
    u32 a2 = *(const u32*)(bond + ((e2.x >> 16) & 0x7Fu) * 128 + lo);
    u32 a3 = *(const u32*)(bond + ((e3.x >> 16) & 0x7Fu) * 128 + lo);
    u32 b0 = *(const u32*)(bondB + ((e0.x >> 23) & 0x7Fu) * 128 + lo);
    u32 b1 = *(const u32*)(bondB + ((e1.x >> 23) & 0x7Fu) * 128 + lo);
    u32 b2 = *(const u32*)(bondB + ((e2.x >> 23) & 0x7Fu) * 128 + lo);
    u32 b3 = *(const u32*)(bondB + ((e3.x >> 23) & 0x7Fu) * 128 + lo);
    u32 c0 = *(const u32*)(bondC + e0.y * 128 + lo);
    u32 c1 = *(const u32*)(bondC + e1.y * 128 + lo);
    u32 c2 = *(const u32*)(bondC + e2.y * 128 + lo);
    u32 c3 = *(const u32*)(bondC + e3.y * 128 + lo);
    acc0 += fmaxf(b2f((u16)h0) + b2f((u16)a0) + b2f((u16)b0) + b2f((u16)c0), 0.f);
    acc1 += fmaxf(b2f((u16)(h0 >> 16)) + b2f((u16)(a0 >> 16)) + b2f((u16)(b0 >> 16)) + b2f((u16)(c0 >> 16)), 0.f);
    acc0 += fmaxf(b2f((u16)h1) + b2f((u16)a1) + b2f((u16)b1) + b2f((u16)c1), 0.f);
    acc1 += fmaxf(b2f((u16)(h1 >> 16)) + b2f((u16)(a1 >> 16)) + b2f((u16)(b1 >> 16)) + b2f((u16)(c1 >> 16)), 0.f);
    acc0 += fmaxf(b2f((u16)h2) + b2f((u16)a2) + b2f((u16)b2) + b2f((u16)c2), 0.f);
    acc1 += fmaxf(b2f((u16)(h2 >> 16)) + b2f((u16)(a2 >> 16)) + b2f((u16)(b2 >> 16)) + b2f((u16)(c2 >> 16)), 0.f);
    acc0 += fmaxf(b2f((u16)h3) + b2f((u16)a3) + b2f((u16)b3) + b2f((u16)c3), 0.f);
    acc1 += fmaxf(b2f((u16)(h3 >> 16)) + b2f((u16)(a3 >> 16)) + b2f((u16)(b3 >> 16)) + b2f((u16)(c3 >> 16)), 0.f);
  }
  for (; p < p1; ++p) {
    uint2 e0 = epack[p];
    u32 h0 = *(const u32*)(h + (size_t)(e0.x & 0xFFFFu) * 128 + lo);
    u32 a0 = *(const u32*)(bond + ((e0.x >> 16) & 0x7Fu) * 128 + lo);
    u32 b0 = *(const u32*)(bondB + ((e0.x >> 23) & 0x7Fu) * 128 + lo);
    u32 c0 = *(const u32*)(bondC + e0.y * 128 + lo);
    acc0 += fmaxf(b2f((u16)h0) + b2f((u16)a0) + b2f((u16)b0) + b2f((u16)c0), 0.f);
    acc1 += fmaxf(b2f((u16)(h0 >> 16)) + b2f((u16)(a0 >> 16)) + b2f((u16)(b0 >> 16)) + b2f((u16)(c0 >> 16)), 0.f);
  }
  float epsf = 1.0f + b2f(epsv[layer]);
  u32 own = *(const u32*)(h + (size_t)node * 128 + lo);
  u32 o = (u32)f2b(epsf * b2f((u16)own) + acc0) |
          ((u32)f2b(epsf * b2f((u16)(own >> 16)) + acc1) << 16);
  *(u32*)(amat + (size_t)node * 128 + lo) = o;
}

// ---- GEMM1: z0 = amat @ W1 + b1 (bf16) + BN1 stats. LDS-staged, BK=64, pre-transposed B. ----
__global__ __launch_bounds__(256)
void k_gemm1(const u16* __restrict__ amat, const u16* __restrict__ w1t,
             const u16* __restrict__ b1, u16* __restrict__ z0,
             float* __restrict__ bnsum, float* __restrict__ bnsq) {
  __shared__ u16 As[128 * 72];
  __shared__ u16 Bs[128 * 72];
  __shared__ float colAcc[256];
  const int tid = threadIdx.x;
  const int r0 = blockIdx.x * 128;
  const int nc = blockIdx.y * 128;
  const int w = tid >> 6, lane = tid & 63, l15 = lane & 15, q = lane >> 4;
  const int wr = (w & 1) * 64, wc = (w >> 1) * 64;
  f32x4 acc[4][4];
#pragma unroll
  for (int i = 0; i < 4; ++i)
#pragma unroll
    for (int j = 0; j < 4; ++j) acc[i][j] = {0.f, 0.f, 0.f, 0.f};

#pragma unroll
  for (int ks = 0; ks < 2; ++ks) {
    const int k0 = ks * 64;
    for (int idx = tid; idx < 1024; idx += 256) {
      const int row = idx >> 3, c8 = (idx & 7) << 3;
      int gr = r0 + row; if (gr >= NN) gr = NN - 1;
      uint4 va = *(const uint4*)(amat + (size_t)gr * 128 + k0 + c8);
      *(uint4*)(As + row * 72 + c8) = va;
      uint4 vb = *(const uint4*)(w1t + (size_t)(nc + row) * 128 + k0 + c8);
      *(uint4*)(Bs + row * 72 + c8) = vb;
    }
    __syncthreads();
#pragma unroll
    for (int kk = 0; kk < 64; kk += 32) {
      const int kf = kk + q * 8;
      bf16x8 a[4], b[4];
#pragma unroll
      for (int i = 0; i < 4; ++i) a[i] = *(const bf16x8*)(As + (wr + i * 16 + l15) * 72 + kf);
#pragma unroll
      for (int j = 0; j < 4; ++j) b[j] = *(const bf16x8*)(Bs + (wc + j * 16 + l15) * 72 + kf);
#pragma unroll
      for (int i = 0; i < 4; ++i)
#pragma unroll
        for (int j = 0; j < 4; ++j)
          acc[i][j] = __builtin_amdgcn_mfma_f32_16x16x32_bf16(a[i], b[j], acc[i][j], 0, 0, 0);
    }
    __syncthreads();
  }
  colAcc[tid] = 0.f;
  __syncthreads();
#pragma unroll
  for (int j = 0; j < 4; ++j) {
    const int c = wc + j * 16 + l15;
    const float bias = b2f(b1[nc + c]);
    float ls = 0.f, lsq = 0.f;
#pragma unroll
    for (int i = 0; i < 4; ++i) {
      const int gr = r0 + wr + i * 16 + q * 4;
#pragma unroll
      for (int rg = 0; rg < 4; ++rg) {
        if (gr + rg < NN) {
          const float v = acc[i][j][rg] + bias;
          z0[(gr + rg) * 256 + nc + c] = f2b(v);
          ls += v;
          lsq += v * v;
        }
      }
    }
    atomicAdd(&colAcc[c], ls);
    atomicAdd(&colAcc[128 + c], lsq);
  }
  __syncthreads();
  if (tid < 128) {
    atomicAdd(&bnsum[nc + tid], colAcc[tid]);
    atomicAdd(&bnsq[nc + tid], colAcc[128 + tid]);
  }
}

// bnfin: fold BN into c1 = rs*g, c0 = beta - m*c1; zero stats for next layer
__global__ void k_bnfin(float* __restrict__ bnsum, float* __restrict__ bnsq,
                        const u16* __restrict__ g, const u16* __restrict__ b,
                        float* __restrict__ c1, float* __restrict__ c0) {
  int t = threadIdx.x;
  float s = bnsum[t], q = bnsq[t];
  bnsum[t] = 0.f;
  bnsq[t] = 0.f;
  float m = s * (1.0f / NN);
  float var = q * (1.0f / NN) - m * m;
  float rs = rsqrtf(var + 1e-5f);
  float cc1 = rs * b2f(g[t]);
  c1[t] = cc1;
  c0[t] = b2f(b[t]) - m * cc1;
}

// ---- GEMM2: hpre = relu(z0*c1+c0) @ W2 + b2 + BN2 stats. BN1 applied during A staging. ----
__global__ __launch_bounds__(256)
void k_gemm2(const u16* __restrict__ z0, const float* __restrict__ c1,
             const float* __restrict__ c0, const u16* __restrict__ w2t,
             const u16* __restrict__ b2, u16* __restrict__ hpre,
             float* __restrict__ bnsum, float* __restrict__ bnsq) {
  __shared__ u16 As[128 * 72];
  __shared__ u16 Bs[128 * 72];
  __shared__ float colAcc[256];
  const int tid = threadIdx.x;
  const int r0 = blockIdx.x * 128;
  const int w = tid >> 6, lane = tid & 63, l15 = lane & 15, q = lane >> 4;
  const int wr = (w & 1) * 64, wc = (w >> 1) * 64;
  f32x4 acc[4][4];
#pragma unroll
  for (int i = 0; i < 4; ++i)
#pragma unroll
    for (int j = 0; j < 4; ++j) acc[i][j] = {0.f, 0.f, 0.f, 0.f};

#pragma unroll
  for (int ks = 0; ks < 4; ++ks) {
    const int k0 = ks * 64;
    for (int idx = tid; idx < 1024; idx += 256) {
      const int row = idx >> 3, c8 = (idx & 7) << 3;
      int gr = r0 + row; if (gr >= NN) gr = NN - 1;
      // A: z0 chunk with BN1+relu applied, rounded to bf16
      ushort4 z01 = *(const ushort4*)(z0 + (size_t)gr * 256 + k0 + c8);
      ushort4 z23 = *(const ushort4*)(z0 + (size_t)gr * 256 + k0 + c8 + 4);
      ushort4 o01, o23;
      {
        const int k = k0 + c8;
        o01.x = f2b(fmaxf(b2f(z01.x) * c1[k + 0] + c0[k + 0], 0.f));
        o01.y = f2b(fmaxf(b2f(z01.y) * c1[k + 1] + c0[k + 1], 0.f));
        o01.z = f2b(fmaxf(b2f(z01.z) * c1[k + 2] + c0[k + 2], 0.f));
        o01.w = f2b(fmaxf(b2f(z01.w) * c1[k + 3] + c0[k + 3], 0.f));
        o23.x = f2b(fmaxf(b2f(z23.x) * c1[k + 4] + c0[k + 4], 0.f));
        o23.y = f2b(fmaxf(b2f(z23.y) * c1[k + 5] + c0[k + 5], 0.f));
        o23.z = f2b(fmaxf(b2f(z23.z) * c1[k + 6] + c0[k + 6], 0.f));
        o23.w = f2b(fmaxf(b2f(z23.w) * c1[k + 7] + c0[k + 7], 0.f));
      }
      *(ushort4*)(As + row * 72 + c8) = o01;
      *(ushort4*)(As + row * 72 + c8 + 4) = o23;
      uint4 vb = *(const uint4*)(w2t + (size_t)row * 256 + k0 + c8);
      *(uint4*)(Bs + row * 72 + c8) = vb;
    }
    __syncthreads();
#pragma unroll
    for (int kk = 0; kk < 64; kk += 32) {
      const int kf = kk + q * 8;
      bf16x8 a[4], b[4];
#pragma unroll
      for (int i = 0; i < 4; ++i) a[i] = *(const bf16x8*)(As + (wr + i * 16 + l15) * 72 + kf);
#pragma unroll
      for (int j = 0; j < 4; ++j) b[j] = *(const bf16x8*)(Bs + (wc + j * 16 + l15) * 72 + kf);
#pragma unroll
      for (int i = 0; i < 4; ++i)
#pragma unroll
        for (int j = 0; j < 4; ++j)
          acc[i][j] = __builtin_amdgcn_mfma_f32_16x16x32_bf16(a[i], b[j], acc[i][j], 0, 0, 0);
    }
    __syncthreads();
  }
  colAcc[tid] = 0.f;
  __syncthreads();
#pragma unroll
  for (int j = 0; j < 4; ++j) {
    const int c = wc + j * 16 + l15;
    const float bias = b2f(b2[c]);
    float ls = 0.f, lsq = 0.f;
#pragma unroll
    for (int i = 0; i < 4; ++i) {
      const int gr = r0 + wr + i * 16 + q * 4;
#pragma unroll
      for (int rg = 0; rg < 4; ++rg) {
        if (gr + rg < NN) {
          const float v = acc[i][j][rg] + bias;
          hpre[(gr + rg) * 128 + c] = f2b(v);
          ls += v;
          lsq += v * v;
        }
      }
    }
    atomicAdd(&colAcc[c], ls);
    atomicAdd(&colAcc[128 + c], lsq);
  }
  __syncthreads();
  if (tid < 128) {
    atomicAdd(&bnsum[tid], colAcc[tid]);
    atomicAdd(&bnsq[tid], colAcc[128 + tid]);
  }
}

// ------- BN2 apply (folded) + relu + write h (vectorized x4) -------
__global__ void k_bnapply(const u16* __restrict__ hpre, const float* __restrict__ c1,
                          const float* __restrict__ c0, u16* __restrict__ h, int dorelu) {
  int idx4 = (blockIdx.x * 256 + threadIdx.x) * 4;
  if (idx4 >= NN * 128) return;
  int f = idx4 & 127;
  const ushort4 hv = *(const ushort4*)(hpre + idx4);
  const float4 rv = *(const float4*)(c1 + f);
  const float4 bv = *(const float4*)(c0 + f);
  float v0 = b2f(hv.x) * rv.x + bv.x;
  float v1 = b2f(hv.y) * rv.y + bv.y;
  float v2 = b2f(hv.z) * rv.z + bv.z;
  float v3 = b2f(hv.w) * rv.w + bv.w;
  if (dorelu) {
    v0 = fmaxf(v0, 0.f); v1 = fmaxf(v1, 0.f);
    v2 = fmaxf(v2, 0.f); v3 = fmaxf(v3, 0.f);
  }
  ushort4 ov;
  ov.x = f2b(v0); ov.y = f2b(v1); ov.z = f2b(v2); ov.w = f2b(v3);
  *(ushort4*)(h + idx4) = ov;
}

// ------- segment pooling, 4 blocks per graph, atomic fp32 into rep -------
__global__ void k_poolseg(const u16* __restrict__ h, const int* __restrict__ gstart,
                          const int* __restrict__ gend, float* __restrict__ rep) {
  int g = blockIdx.x >> 2, part = blockIdx.x & 3, f = threadIdx.x;  // 128 threads
  int r0 = gstart[g], r1 = gend[g] + 1;
  int len = r1 - r0;
  if (len <= 0) return;
  int chunk = (len + 3) >> 2;
  int s = r0 + part * chunk;
  int e = s + chunk; if (e > r1) e = r1;
  float acc = 0.f;
  for (int r = s; r < e; ++r) acc += b2f(h[r * 128 + f]);
  if (s < e) atomicAdd(&rep[g * 128 + f], acc);
}

// mean-divide; also emit bf16 copy for the MFMA FC head
__global__ void k_rep(float* __restrict__ rep, const int* __restrict__ gstart,
                      const int* __restrict__ gend, u16* __restrict__ repb) {
  int idx = blockIdx.x * 256 + threadIdx.x;  // GG*128
  int g = idx >> 7;
  int c = gend[g] - gstart[g] + 1;
  if (c < 1) c = 1;
  float v = rep[idx] / (float)c;
  rep[idx] = v;
  repb[idx] = f2b(v);
}

// ---- FC layer via MFMA: out[256][N] = relu(A[256][K] @ Wt[N][K]^T + bias) (bf16) ----
__global__ __launch_bounds__(256)
void k_fcg(const u16* __restrict__ A, const u16* __restrict__ Wt,
           const u16* __restrict__ bias, u16* __restrict__ out, int K, int N) {
  const int tid = threadIdx.x;
  const int r0 = blockIdx.x * 128;
  const int nc = blockIdx.y * 128;
  const int w = tid >> 6, lane = tid & 63, l15 = lane & 15, q = lane >> 4;
  const int wr = (w & 1) * 64, wc = (w >> 1) * 64;
  f32x4 acc[4][4];
#pragma unroll
  for (int i = 0; i < 4; ++i)
#pragma unroll
    for (int j = 0; j < 4; ++j) acc[i][j] = {0.f, 0.f, 0.f, 0.f};
  const int nkb = K >> 5;
  for (int kb = 0; kb < nkb; ++kb) {
    const int kf = kb * 32 + q * 8;
    bf16x8 a[4], b[4];
#pragma unroll
    for (int i = 0; i < 4; ++i)
      a[i] = *(const bf16x8*)(A + (size_t)(r0 + wr + i * 16 + l15) * K + kf);
#pragma unroll
    for (int j = 0; j < 4; ++j)
      b[j] = *(const bf16x8*)(Wt + (size_t)(nc + wc + j * 16 + l15) * K + kf);
#pragma unroll
    for (int i = 0; i < 4; ++i)
#pragma unroll
      for (int j = 0; j < 4; ++j)
        acc[i][j] = __builtin_amdgcn_mfma_f32_16x16x32_bf16(a[i], b[j], acc[i][j], 0, 0, 0);
  }
#pragma unroll
  for (int j = 0; j < 4; ++j) {
    const int c = nc + wc + j * 16 + l15;
    const float bv = b2f(bias[c]);
#pragma unroll
    for (int i = 0; i < 4; ++i) {
      const int gr = r0 + wr + i * 16 + q * 4;
#pragma unroll
      for (int rg = 0; rg < 4; ++rg)
        out[(gr + rg) * N + c] = f2b(fmaxf(acc[i][j][rg] + bv, 0.f));
    }
  }
}

__global__ void k_fc4(const u16* __restrict__ z, const u16* __restrict__ W,
                      const u16* __restrict__ bias, void* __restrict__ out,
                      const int* __restrict__ flag) {
  int g = blockIdx.x, lane = threadIdx.x;  // 64 threads
  float acc = 0.f;
  for (int k = lane; k < 512; k += 64) acc += b2f(z[g * 512 + k]) * b2f(W[k]);
  for (int off = 32; off > 0; off >>= 1) acc += __shfl_down(acc, off);
  if (lane == 0) {
    float r = acc + b2f(bias[0]);
    if (flag[0]) ((float*)out)[g] = r;
    else ((u16*)out)[g] = f2b(r);
  }
}

extern "C" void kernel_launch(void* const* d_in, const int* in_sizes, int n_in,
                              void* d_out, int out_size, void* d_ws, size_t ws_size,
                              hipStream_t stream) {
  const int* x     = (const int*)d_in[0];
  const int* ei    = (const int*)d_in[1];
  const int* eattr = (const int*)d_in[2];
  const int* batch = (const int*)d_in[3];

  char* ws = (char*)d_ws;
  size_t off = 0;
  auto alloc = [&](size_t bytes) -> void* {
    void* p = ws + off;
    off += (bytes + 255) & ~(size_t)255;
    return p;
  };
  int* flag = (int*)alloc(256);
  u16* cvt[23];
  CvtArgs ca;
  ca.cum[0] = 0;
  for (int i = 4; i <= 22; ++i) {
    cvt[i] = (u16*)alloc((size_t)in_sizes[i] * 2);
    ca.src[i - 4] = d_in[i];
    ca.dst[i - 4] = cvt[i];
    ca.cum[i - 3] = ca.cum[i - 4] + in_sizes[i];
  }

  u16*   h      = (u16*)  alloc((size_t)NN * 128 * 2);   // 12.8 MB
  u16*   amat   = (u16*)  alloc((size_t)NN * 128 * 2);   // 12.8 MB (aliases hpre)
  u16*   z0     = (u16*)  alloc((size_t)NN * 256 * 2);   // 25.6 MB
  u16*   w1t    = (u16*)  alloc(32768 * 2);
  u16*   w2t    = (u16*)  alloc(32768 * 2);
  u16*   ft1    = (u16*)  alloc((size_t)1024 * 128 * 2);
  u16*   ft2    = (u16*)  alloc((size_t)1024 * 1024 * 2);
  u16*   ft3    = (u16*)  alloc((size_t)512 * 1024 * 2);
  int*   deg    = (int*)  alloc((size_t)NN * 4);
  int*   cursor = (int*)  alloc((size_t)NN * 4);
  int*   rowp   = (int*)  alloc((size_t)(NN + 1) * 4);
  int*   bsum   = (int*)  alloc((size_t)NB * 4);
  int*   boff   = (int*)  alloc((size_t)NB * 4);
  uint2* epack  = (uint2*)alloc((size_t)EE * 8);         // 4.8 MB
  float* bnbuf  = (float*)alloc(768 * 4);
  float* bnstat = (float*)alloc(1152 * 4);
  float* rep    = (float*)alloc((size_t)GG * 128 * 4);
  u16*   repb   = (u16*)  alloc((size_t)GG * 128 * 2);
  int*   gstart = (int*)  alloc((size_t)GG * 4);
  int*   gend   = (int*)  alloc((size_t)GG * 4);
  u16*   fz1    = (u16*)  alloc((size_t)GG * 1024 * 2);
  u16*   fz2    = (u16*)  alloc((size_t)GG * 1024 * 2);
  u16*   fz3    = (u16*)  alloc((size_t)GG * 512 * 2);
  (void)ws_size; (void)n_in; (void)out_size;

  u16* hpre = amat;  // disjoint lifetimes

  float* bn1sum = bnbuf;
  float* bn1sq  = bnbuf + 256;
  float* bn2sum = bnbuf + 512;
  float* bn2sq  = bnbuf + 640;
  float* c1a    = bnstat;          // BN1 folded scale (256)
  float* c0a    = bnstat + 256;    // BN1 folded shift (256)
  float* c1b    = bnstat + 512;    // BN2 folded scale (128)
  float* c0b    = bnstat + 640;    // BN2 folded shift (128)

  k_detect<<<1, 256, 0, stream>>>((const u32*)d_in[4], flag);
  {
    int total = ca.cum[19];
    k_cvt_all<<<(total + 255) / 256, 256, 0, stream>>>(ca, flag);
  }
  const u16 *aembc = cvt[4], *bembc = cvt[5], *epsc = cvt[6], *w1c = cvt[7],
            *b1c = cvt[8], *g1c = cvt[9], *be1c = cvt[10], *w2c = cvt[11],
            *b2c = cvt[12], *bngc = cvt[13], *bnbc = cvt[14], *fw1 = cvt[15],
            *fb1 = cvt[16], *fw2 = cvt[17], *fb2 = cvt[18], *fw3 = cvt[19],
            *fb3 = cvt[20], *fw4 = cvt[21], *fb4 = cvt[22];

  k_tr<<<128, 256, 0, stream>>>(w1c, w1t, 128, 256);
  k_tr<<<128, 256, 0, stream>>>(w2c, w2t, 256, 128);
  k_tr<<<512, 256, 0, stream>>>(fw1, ft1, 128, 1024);
  k_tr<<<4096, 256, 0, stream>>>(fw2, ft2, 1024, 1024);
  k_tr<<<2048, 256, 0, stream>>>(fw3, ft3, 1024, 512);

  hipMemsetAsync(deg, 0, (size_t)NN * 4, stream);
  hipMemsetAsync(rep, 0, (size_t)GG * 128 * 4, stream);
  hipMemsetAsync(gstart, 0x7F, (size_t)GG * 4, stream);
  hipMemsetAsync(gend, 0xFF, (size_t)GG * 4, stream);
  hipMemsetAsync(bnbuf, 0, 768 * 4, stream);
  k_deg<<<(EE + 255) / 256, 256, 0, stream>>>(ei, deg);
  k_scan1<<<NB, 256, 0, stream>>>(deg, rowp, bsum);
  k_scan2<<<1, 256, 0, stream>>>(bsum, boff);
  k_scan3<<<NB, 256, 0, stream>>>(rowp, boff, cursor);
  k_fill<<<(EE + 255) / 256, 256, 0, stream>>>(ei, eattr, cursor, epack);
  k_gb<<<(NN + 255) / 256, 256, 0, stream>>>(batch, gstart, gend);
  k_atom<<<(NN * 64 + 255) / 256, 256, 0, stream>>>(x, aembc, h);
  k_poolseg<<<GG * 4, 128, 0, stream>>>(h, gstart, gend, rep);

  const int gx = (NN + 127) / 128;  // 391
  for (int l = 0; l < LL; ++l) {
    k_pull<<<(NN + 3) / 4, 256, 0, stream>>>(h, rowp, epack,
                                             bembc + (size_t)l * 3 * 128 * 128, epsc, l, amat);
    dim3 grid1(gx, 2);
    k_gemm1<<<grid1, 256, 0, stream>>>(amat, w1t, b1c, z0, bn1sum, bn1sq);
    k_bnfin<<<1, 256, 0, stream>>>(bn1sum, bn1sq, g1c, be1c, c1a, c0a);
    k_gemm2<<<gx, 256, 0, stream>>>(z0, c1a, c0a, w2t, b2c, hpre, bn2sum, bn2sq);
    k_bnfin<<<1, 128, 0, stream>>>(bn2sum, bn2sq, bngc + l * 128, bnbc + l * 128,
                                   c1b, c0b);
    k_bnapply<<<(NN * 128) / 1024, 256, 0, stream>>>(hpre, c1b, c0b, h,
                                                     (l < LL - 1) ? 1 : 0);
    k_poolseg<<<GG * 4, 128, 0, stream>>>(h, gstart, gend, rep);
  }

  k_rep<<<(GG * 128) / 256, 256, 0, stream>>>(rep, gstart, gend, repb);
  {
    dim3 g1(2, 8), g2(2, 8), g3(2, 4);
    k_fcg<<<g1, 256, 0, stream>>>(repb, ft1, fb1, fz1, 128, 1024);
    k_fcg<<<g2, 256, 0, stream>>>(fz1, ft2, fb2, fz2, 1024, 1024);
    k_fcg<<<g3, 256, 0, stream>>>(fz2, ft3, fb3, fz3, 1024, 512);
  }
  k_fc4<<<GG, 64, 0, stream>>>(fz3, fw4, fb4, d_out, flag);
}